// Round 2
// baseline (281.056 us; speedup 1.0000x reference)
//
#include <hip/hip_runtime.h>
#include <hip/hip_bf16.h>
#include <stdint.h>
#include <math.h>

using bf16x8 = __attribute__((ext_vector_type(8))) short;
using f32x4  = __attribute__((ext_vector_type(4))) float;

#define NHEAD  16
#define DK     64
#define TSEQ   2048
#define DMODEL 1024
#define MTOT   4096   // B*T

static __device__ __forceinline__ ushort f2bf(float f) {
  union { float f; uint32_t u; } v; v.f = f;
  return (ushort)((v.u + 0x7FFFu + ((v.u >> 16) & 1u)) >> 16);   // RNE
}

static __device__ __forceinline__ void gload_lds16(const ushort* g, ushort* l) {
  typedef __attribute__((address_space(1))) const uint32_t gu32;
  typedef __attribute__((address_space(3))) uint32_t lu32;
  __builtin_amdgcn_global_load_lds((gu32*)g, (lu32*)l, 16, 0, 0);
}

// ---------- f32 -> bf16 elementwise (vectorized, G13) ----------
__global__ void cvt_bf16_kernel(const float* __restrict__ in, ushort* __restrict__ out, int n) {
  int i = (blockIdx.x * 256 + threadIdx.x) * 8;
  const int stride = gridDim.x * 256 * 8;
  for (; i < n; i += stride) {
    const float4* p = (const float4*)(in + i);
    float4 a = p[0], b = p[1];
    bf16x8 v;
    v[0]=(short)f2bf(a.x); v[1]=(short)f2bf(a.y); v[2]=(short)f2bf(a.z); v[3]=(short)f2bf(a.w);
    v[4]=(short)f2bf(b.x); v[5]=(short)f2bf(b.y); v[6]=(short)f2bf(b.z); v[7]=(short)f2bf(b.w);
    *(bf16x8*)(out + i) = v;
  }
}

// ---------- W[K][N] f32  ->  Wt[N][K] bf16 (LDS-tiled transpose) ----------
__global__ __launch_bounds__(256) void transpose_cvt_kernel(const float* __restrict__ W,
                                                            ushort* __restrict__ Wt, int K, int N) {
  __shared__ ushort tl[64][66];  // pad 66 -> conflict-free phase-2 reads
  const int n0 = blockIdx.x * 64, k0 = blockIdx.y * 64;
  const int c = threadIdx.x & 63, r0 = threadIdx.x >> 6;
#pragma unroll
  for (int i = 0; i < 64; i += 4)
    tl[i + r0][c] = f2bf(W[(size_t)(k0 + i + r0) * N + n0 + c]);
  __syncthreads();
#pragma unroll
  for (int i = 0; i < 64; i += 4)
    Wt[(size_t)(n0 + i + r0) * K + k0 + c] = tl[c][i + r0];
}

// ---------- V[bh][T][64] bf16 -> Vt[bh][64][T] bf16 ----------
__global__ __launch_bounds__(256) void transpose_v_kernel(const ushort* __restrict__ V,
                                                          ushort* __restrict__ Vt) {
  __shared__ ushort tl[64][66];
  const int bh = blockIdx.y, t0 = blockIdx.x * 64;
  const int c = threadIdx.x & 63, r0 = threadIdx.x >> 6;
  const ushort* Vb = V + (size_t)bh * TSEQ * DK;
  ushort* Vtb = Vt + (size_t)bh * DK * TSEQ;
#pragma unroll
  for (int i = 0; i < 64; i += 4)
    tl[i + r0][c] = Vb[(size_t)(t0 + i + r0) * DK + c];
  __syncthreads();
#pragma unroll
  for (int i = 0; i < 64; i += 4)
    Vtb[(size_t)(i + r0) * TSEQ + t0 + c] = tl[c][i + r0];
}

// ---------- m97-style bf16 GEMM, C = A[M][K] * Bt[N][K]^T + bias ----------
// MODE 0: epilogue scatters K,Q,V (bf16) into [B,H,T,dk];  MODE 1: fp32 out [M][N]
template <int MODE>
__global__ __launch_bounds__(256, 2)
void gemm_bt_kernel(const ushort* __restrict__ A, const ushort* __restrict__ Bt,
                    const float* __restrict__ bias,
                    ushort* __restrict__ oK, ushort* __restrict__ oQ, ushort* __restrict__ oV,
                    float* __restrict__ oF, int N, int K) {
  __shared__ ushort As[128 * 32];
  __shared__ ushort Bs[128 * 32];
  const int tid = threadIdx.x;
  const int w = tid >> 6, lane = tid & 63;
  const int m0 = blockIdx.y * 128, n0 = blockIdx.x * 128;
  const int wr = (w >> 1) * 64, wc = (w & 1) * 64;

  // staging geometry: lane i of wave w covers LDS bytes (w*2+is)*1024 + lane*16 (linear)
  const int e0 = ((w * 2 + 0) * 64 + lane) * 8;
  const int e1 = ((w * 2 + 1) * 64 + lane) * 8;
  const ushort* pA0 = A  + (size_t)(m0 + (e0 >> 5)) * K + (e0 & 31);
  const ushort* pA1 = A  + (size_t)(m0 + (e1 >> 5)) * K + (e1 & 31);
  const ushort* pB0 = Bt + (size_t)(n0 + (e0 >> 5)) * K + (e0 & 31);
  const ushort* pB1 = Bt + (size_t)(n0 + (e1 >> 5)) * K + (e1 & 31);

  f32x4 acc[4][4];
#pragma unroll
  for (int i = 0; i < 4; i++)
#pragma unroll
    for (int j = 0; j < 4; j++) acc[i][j] = (f32x4){0.f, 0.f, 0.f, 0.f};

  const int aro = (wr + (lane & 15)) * 32 + (lane >> 4) * 8;  // A-frag base (elems)
  const int bro = (wc + (lane & 15)) * 32 + (lane >> 4) * 8;  // B-frag base

  for (int k0 = 0; k0 < K; k0 += 32) {
    __syncthreads();
    gload_lds16(pA0 + k0, &As[e0]);
    gload_lds16(pA1 + k0, &As[e1]);
    gload_lds16(pB0 + k0, &Bs[e0]);
    gload_lds16(pB1 + k0, &Bs[e1]);
    __syncthreads();
    bf16x8 af[4], bfr[4];
#pragma unroll
    for (int i = 0; i < 4; i++) af[i]  = *(const bf16x8*)&As[aro + i * 16 * 32];
#pragma unroll
    for (int j = 0; j < 4; j++) bfr[j] = *(const bf16x8*)&Bs[bro + j * 16 * 32];
#pragma unroll
    for (int i = 0; i < 4; i++)
#pragma unroll
      for (int j = 0; j < 4; j++)
        acc[i][j] = __builtin_amdgcn_mfma_f32_16x16x32_bf16(af[i], bfr[j], acc[i][j], 0, 0, 0);
  }

  // C/D layout: col = lane&15, row = (lane>>4)*4 + reg  [m89-verified]
  const int rbase = m0 + wr + (lane >> 4) * 4;
  const int cbase = n0 + wc + (lane & 15);
#pragma unroll
  for (int i = 0; i < 4; i++) {
#pragma unroll
    for (int j = 0; j < 4; j++) {
      const int gn = cbase + j * 16;
      const float bv = bias[gn];
#pragma unroll
      for (int jj = 0; jj < 4; jj++) {
        const int gm = rbase + i * 16 + jj;
        const float val = acc[i][j][jj] + bv;
        if (MODE == 0) {
          const int sel = gn >> 10, cc = gn & 1023;
          const int h = cc >> 6, dd = cc & 63;
          const int bb = gm >> 11, t = gm & 2047;
          ushort* dst = (sel == 0) ? oK : (sel == 1) ? oQ : oV;
          dst[((size_t)((bb * NHEAD + h) * TSEQ + t)) * DK + dd] = f2bf(val);
        } else {
          oF[(size_t)gm * N + gn] = val;
        }
      }
    }
  }
}

// ---------- causal flash attention: 1 block = 1 head x 128 Q-rows ----------
__global__ __launch_bounds__(256, 2)
void attn_kernel(const ushort* __restrict__ Qb, const ushort* __restrict__ Kb,
                 const ushort* __restrict__ Vtb, ushort* __restrict__ O) {
  __shared__ ushort Ks[64 * 64];       // [s][dk], XOR-swizzled 16B blocks
  __shared__ ushort Vs[64 * 64];       // [dk][s], XOR-swizzled
  __shared__ ushort Ps[4][32 * 64];    // per-wave P tile, XOR-swizzled

  const int bid = blockIdx.x;
  const int bh = bid >> 4;
  const int qi = 15 - (bid & 15);      // longest blocks first (LPT)
  const int q0 = qi * 128;
  const int bb = bh >> 4, h = bh & 15;
  const int tid = threadIdx.x, w = tid >> 6, lane = tid & 63;
  const int l15 = lane & 15, l4 = lane >> 4;

  // Q fragments live in registers for the whole block (A-operand layout)
  const ushort* Qp = Qb + ((size_t)bh * TSEQ + q0 + w * 32) * DK;
  bf16x8 qf[2][2];
#pragma unroll
  for (int m = 0; m < 2; m++)
#pragma unroll
    for (int c = 0; c < 2; c++)
      qf[m][c] = *(const bf16x8*)(Qp + (m * 16 + l15) * DK + c * 32 + l4 * 8);

  f32x4 oacc[2][4];
  float mrun[2][4], lrun[2][4];
#pragma unroll
  for (int m = 0; m < 2; m++) {
#pragma unroll
    for (int n = 0; n < 4; n++) oacc[m][n] = (f32x4){0.f, 0.f, 0.f, 0.f};
#pragma unroll
    for (int jj = 0; jj < 4; jj++) { mrun[m][jj] = -INFINITY; lrun[m][jj] = 0.f; }
  }

  // staging: linear LDS dest + inverse-swizzled global source (rule #21)
  const int Bl0 = w * 128 + lane, Bl1 = Bl0 + 64;
  const int sr0 = Bl0 >> 3, sc0 = ((Bl0 & 7) ^ (sr0 & 7)) * 8;
  const int sr1 = Bl1 >> 3, sc1 = ((Bl1 & 7) ^ (sr1 & 7)) * 8;
  const ushort* Kp0 = Kb  + (size_t)bh * TSEQ * DK + sr0 * DK + sc0;
  const ushort* Kp1 = Kb  + (size_t)bh * TSEQ * DK + sr1 * DK + sc1;
  const ushort* Vp0 = Vtb + (size_t)bh * DK * TSEQ + sr0 * TSEQ + sc0;
  const ushort* Vp1 = Vtb + (size_t)bh * DK * TSEQ + sr1 * TSEQ + sc1;

  ushort* Pw = &Ps[w][0];
  const int nt = (q0 + 128) >> 6;

  for (int ti = 0; ti < nt; ti++) {
    const int s0 = ti * 64;
    __syncthreads();
    gload_lds16(Kp0 + s0 * DK, &Ks[Bl0 * 8]);
    gload_lds16(Kp1 + s0 * DK, &Ks[Bl1 * 8]);
    gload_lds16(Vp0 + s0, &Vs[Bl0 * 8]);
    gload_lds16(Vp1 + s0, &Vs[Bl1 * 8]);
    __syncthreads();

    // S = Q K^T
    f32x4 s[2][4];
#pragma unroll
    for (int n = 0; n < 4; n++) {
      const int krow = n * 16 + l15;
      const int sw = (krow & 7) << 4;
      bf16x8 kf0 = *(const bf16x8*)((const char*)Ks + krow * 128 + ((l4 * 16) ^ sw));
      bf16x8 kf1 = *(const bf16x8*)((const char*)Ks + krow * 128 + ((64 + l4 * 16) ^ sw));
#pragma unroll
      for (int m = 0; m < 2; m++) {
        f32x4 z = (f32x4){0.f, 0.f, 0.f, 0.f};
        z = __builtin_amdgcn_mfma_f32_16x16x32_bf16(qf[m][0], kf0, z, 0, 0, 0);
        z = __builtin_amdgcn_mfma_f32_16x16x32_bf16(qf[m][1], kf1, z, 0, 0, 0);
        s[m][n] = z;
      }
    }

    const bool need_mask = (s0 >= q0);
    // online softmax (fp32); rows live in 16-lane groups -> shfl_xor reduce
#pragma unroll
    for (int m = 0; m < 2; m++) {
#pragma unroll
      for (int jj = 0; jj < 4; jj++) {
        const int row = q0 + w * 32 + m * 16 + l4 * 4 + jj;
        float v0 = s[m][0][jj] * 0.125f, v1 = s[m][1][jj] * 0.125f;
        float v2 = s[m][2][jj] * 0.125f, v3 = s[m][3][jj] * 0.125f;
        if (need_mask) {
          if (s0 +  0 + l15 > row) v0 = -INFINITY;
          if (s0 + 16 + l15 > row) v1 = -INFINITY;
          if (s0 + 32 + l15 > row) v2 = -INFINITY;
          if (s0 + 48 + l15 > row) v3 = -INFINITY;
        }
        float tm = fmaxf(fmaxf(v0, v1), fmaxf(v2, v3));
        tm = fmaxf(tm, __shfl_xor(tm, 1));
        tm = fmaxf(tm, __shfl_xor(tm, 2));
        tm = fmaxf(tm, __shfl_xor(tm, 4));
        tm = fmaxf(tm, __shfl_xor(tm, 8));
        const float nm  = fmaxf(mrun[m][jj], tm);
        const float scl = __expf(mrun[m][jj] - nm);
        mrun[m][jj] = nm;
        v0 = __expf(v0 - nm); v1 = __expf(v1 - nm);
        v2 = __expf(v2 - nm); v3 = __expf(v3 - nm);
        float rs = v0 + v1 + v2 + v3;
        rs += __shfl_xor(rs, 1); rs += __shfl_xor(rs, 2);
        rs += __shfl_xor(rs, 4); rs += __shfl_xor(rs, 8);
        lrun[m][jj] = lrun[m][jj] * scl + rs;
        s[m][0][jj] = v0; s[m][1][jj] = v1; s[m][2][jj] = v2; s[m][3][jj] = v3;
        oacc[m][0][jj] *= scl; oacc[m][1][jj] *= scl;
        oacc[m][2][jj] *= scl; oacc[m][3][jj] *= scl;
      }
    }

    // C-layout P -> A-layout fragments via per-wave swizzled LDS tile
#pragma unroll
    for (int m = 0; m < 2; m++)
#pragma unroll
      for (int jj = 0; jj < 4; jj++) {
        const int prow = m * 16 + l4 * 4 + jj;
        const int sw = (prow & 7) << 4;
        char* rp = (char*)Pw + prow * 128;
#pragma unroll
        for (int n = 0; n < 4; n++) {
          const int cb = (n * 16 + l15) * 2;
          *(ushort*)(rp + (cb ^ sw)) = f2bf(s[m][n][jj]);
        }
      }

    bf16x8 vf[4][2];
#pragma unroll
    for (int n = 0; n < 4; n++) {
      const int vrow = n * 16 + l15;
      const int sw = (vrow & 7) << 4;
      vf[n][0] = *(const bf16x8*)((const char*)Vs + vrow * 128 + ((l4 * 16) ^ sw));
      vf[n][1] = *(const bf16x8*)((const char*)Vs + vrow * 128 + ((64 + l4 * 16) ^ sw));
    }
#pragma unroll
    for (int m = 0; m < 2; m++) {
      const int prow = m * 16 + l15;
      const int sw = (prow & 7) << 4;
      bf16x8 pf0 = *(const bf16x8*)((const char*)Pw + prow * 128 + ((l4 * 16) ^ sw));
      bf16x8 pf1 = *(const bf16x8*)((const char*)Pw + prow * 128 + ((64 + l4 * 16) ^ sw));
#pragma unroll
      for (int n = 0; n < 4; n++) {
        oacc[m][n] = __builtin_amdgcn_mfma_f32_16x16x32_bf16(pf0, vf[n][0], oacc[m][n], 0, 0, 0);
        oacc[m][n] = __builtin_amdgcn_mfma_f32_16x16x32_bf16(pf1, vf[n][1], oacc[m][n], 0, 0, 0);
      }
    }
  }

  // normalize + store attn output as bf16 in [B][T][H*dk]
#pragma unroll
  for (int m = 0; m < 2; m++)
#pragma unroll
    for (int jj = 0; jj < 4; jj++) {
      const float inv = 1.f / lrun[m][jj];
      const int t = q0 + w * 32 + m * 16 + l4 * 4 + jj;
      ushort* orow = O + ((size_t)bb * TSEQ + t) * DMODEL + h * DK;
#pragma unroll
      for (int n = 0; n < 4; n++)
        orow[n * 16 + l15] = f2bf(oacc[m][n][jj] * inv);
    }
}

extern "C" void kernel_launch(void* const* d_in, const int* in_sizes, int n_in,
                              void* d_out, int out_size, void* d_ws, size_t ws_size,
                              hipStream_t stream) {
  (void)in_sizes; (void)n_in; (void)out_size; (void)ws_size;
  const float* x    = (const float*)d_in[0];
  const float* Wkqv = (const float*)d_in[1];
  const float* bkqv = (const float*)d_in[2];
  const float* Wo   = (const float*)d_in[3];
  const float* bo   = (const float*)d_in[4];
  float* out = (float*)d_out;

  char* ws = (char*)d_ws;
  const size_t MB = 1024 * 1024;
  ushort* x_bf   = (ushort*)(ws + 0);        //  8 MB [4096][1024]
  ushort* wkqv_t = (ushort*)(ws + 8 * MB);   //  6 MB [3072][1024]
  ushort* wo_t   = (ushort*)(ws + 14 * MB);  //  2 MB [1024][1024]
  ushort* Kbuf   = (ushort*)(ws + 16 * MB);  //  8 MB [32][2048][64]
  ushort* Qbuf   = (ushort*)(ws + 24 * MB);  //  8 MB
  ushort* Vbuf   = (ushort*)(ws + 32 * MB);  //  8 MB
  ushort* Vtbuf  = (ushort*)(ws + 40 * MB);  //  8 MB [32][64][2048]
  ushort* AObuf  = (ushort*)(ws + 48 * MB);  //  8 MB [4096][1024]

  cvt_bf16_kernel<<<2048, 256, 0, stream>>>(x, x_bf, MTOT * DMODEL);
  transpose_cvt_kernel<<<dim3(3072 / 64, 1024 / 64), 256, 0, stream>>>(Wkqv, wkqv_t, 1024, 3072);
  transpose_cvt_kernel<<<dim3(1024 / 64, 1024 / 64), 256, 0, stream>>>(Wo, wo_t, 1024, 1024);
  gemm_bt_kernel<0><<<dim3(3072 / 128, 4096 / 128), 256, 0, stream>>>(
      x_bf, wkqv_t, bkqv, Kbuf, Qbuf, Vbuf, nullptr, 3072, 1024);
  transpose_v_kernel<<<dim3(TSEQ / 64, 32), 256, 0, stream>>>(Vbuf, Vtbuf);
  attn_kernel<<<512, 256, 0, stream>>>(Qbuf, Kbuf, Vtbuf, AObuf);
  gemm_bt_kernel<1><<<dim3(1024 / 128, 4096 / 128), 256, 0, stream>>>(
      AObuf, wo_t, bo, nullptr, nullptr, nullptr, out, 1024, 1024);
}

// Round 3
// 255.871 us; speedup vs baseline: 1.0984x; 1.0984x over previous
//
#include <hip/hip_runtime.h>
#include <hip/hip_bf16.h>
#include <stdint.h>
#include <math.h>

using bf16x8 = __attribute__((ext_vector_type(8))) short;
using f32x4  = __attribute__((ext_vector_type(4))) float;

#define NHEAD  16
#define DK     64
#define TSEQ   2048
#define DMODEL 1024
#define MTOT   4096   // B*T

static __device__ __forceinline__ ushort f2bf(float f) {
  union { float f; uint32_t u; } v; v.f = f;
  return (ushort)((v.u + 0x7FFFu + ((v.u >> 16) & 1u)) >> 16);   // RNE
}

static __device__ __forceinline__ void gload_lds16(const ushort* g, ushort* l) {
  typedef __attribute__((address_space(1))) const uint32_t gu32;
  typedef __attribute__((address_space(3))) uint32_t lu32;
  __builtin_amdgcn_global_load_lds((gu32*)g, (lu32*)l, 16, 0, 0);
}

// ---------- f32 -> bf16 elementwise (vectorized, G13) ----------
__global__ void cvt_bf16_kernel(const float* __restrict__ in, ushort* __restrict__ out, int n) {
  int i = (blockIdx.x * 256 + threadIdx.x) * 8;
  const int stride = gridDim.x * 256 * 8;
  for (; i < n; i += stride) {
    const float4* p = (const float4*)(in + i);
    float4 a = p[0], b = p[1];
    bf16x8 v;
    v[0]=(short)f2bf(a.x); v[1]=(short)f2bf(a.y); v[2]=(short)f2bf(a.z); v[3]=(short)f2bf(a.w);
    v[4]=(short)f2bf(b.x); v[5]=(short)f2bf(b.y); v[6]=(short)f2bf(b.z); v[7]=(short)f2bf(b.w);
    *(bf16x8*)(out + i) = v;
  }
}

// ---------- W[K][N] f32  ->  Wt[N][K] bf16 (LDS-tiled transpose) ----------
__global__ __launch_bounds__(256) void transpose_cvt_kernel(const float* __restrict__ W,
                                                            ushort* __restrict__ Wt, int K, int N) {
  __shared__ ushort tl[64][66];  // pad 66 -> conflict-free phase-2 reads
  const int n0 = blockIdx.x * 64, k0 = blockIdx.y * 64;
  const int c = threadIdx.x & 63, r0 = threadIdx.x >> 6;
#pragma unroll
  for (int i = 0; i < 64; i += 4)
    tl[i + r0][c] = f2bf(W[(size_t)(k0 + i + r0) * N + n0 + c]);
  __syncthreads();
#pragma unroll
  for (int i = 0; i < 64; i += 4)
    Wt[(size_t)(n0 + i + r0) * K + k0 + c] = tl[c][i + r0];
}

// ---------- V[bh][T][64] bf16 -> Vt[bh][64][T] bf16 ----------
__global__ __launch_bounds__(256) void transpose_v_kernel(const ushort* __restrict__ V,
                                                          ushort* __restrict__ Vt) {
  __shared__ ushort tl[64][66];
  const int bh = blockIdx.y, t0 = blockIdx.x * 64;
  const int c = threadIdx.x & 63, r0 = threadIdx.x >> 6;
  const ushort* Vb = V + (size_t)bh * TSEQ * DK;
  ushort* Vtb = Vt + (size_t)bh * DK * TSEQ;
#pragma unroll
  for (int i = 0; i < 64; i += 4)
    tl[i + r0][c] = Vb[(size_t)(t0 + i + r0) * DK + c];
  __syncthreads();
#pragma unroll
  for (int i = 0; i < 64; i += 4)
    Vtb[(size_t)(i + r0) * TSEQ + t0 + c] = tl[c][i + r0];
}

// ---------- m97-style bf16 GEMM, C = A[M][K] * Bt[N][K]^T + bias ----------
// MODE 0: epilogue scatters K,Q,V (bf16) into [B,H,T,dk];  MODE 1: fp32 out [M][N]
template <int MODE>
__global__ __launch_bounds__(256, 2)
void gemm_bt_kernel(const ushort* __restrict__ A, const ushort* __restrict__ Bt,
                    const float* __restrict__ bias,
                    ushort* __restrict__ oK, ushort* __restrict__ oQ, ushort* __restrict__ oV,
                    float* __restrict__ oF, int N, int K) {
  __shared__ ushort As[128 * 32];
  __shared__ ushort Bs[128 * 32];
  const int tid = threadIdx.x;
  const int w = tid >> 6, lane = tid & 63;
  const int m0 = blockIdx.y * 128, n0 = blockIdx.x * 128;
  const int wr = (w >> 1) * 64, wc = (w & 1) * 64;

  const int e0 = ((w * 2 + 0) * 64 + lane) * 8;
  const int e1 = ((w * 2 + 1) * 64 + lane) * 8;
  const ushort* pA0 = A  + (size_t)(m0 + (e0 >> 5)) * K + (e0 & 31);
  const ushort* pA1 = A  + (size_t)(m0 + (e1 >> 5)) * K + (e1 & 31);
  const ushort* pB0 = Bt + (size_t)(n0 + (e0 >> 5)) * K + (e0 & 31);
  const ushort* pB1 = Bt + (size_t)(n0 + (e1 >> 5)) * K + (e1 & 31);

  f32x4 acc[4][4];
#pragma unroll
  for (int i = 0; i < 4; i++)
#pragma unroll
    for (int j = 0; j < 4; j++) acc[i][j] = (f32x4){0.f, 0.f, 0.f, 0.f};

  const int aro = (wr + (lane & 15)) * 32 + (lane >> 4) * 8;
  const int bro = (wc + (lane & 15)) * 32 + (lane >> 4) * 8;

  for (int k0 = 0; k0 < K; k0 += 32) {
    __syncthreads();
    gload_lds16(pA0 + k0, &As[e0]);
    gload_lds16(pA1 + k0, &As[e1]);
    gload_lds16(pB0 + k0, &Bs[e0]);
    gload_lds16(pB1 + k0, &Bs[e1]);
    __syncthreads();
    bf16x8 af[4], bfr[4];
#pragma unroll
    for (int i = 0; i < 4; i++) af[i]  = *(const bf16x8*)&As[aro + i * 16 * 32];
#pragma unroll
    for (int j = 0; j < 4; j++) bfr[j] = *(const bf16x8*)&Bs[bro + j * 16 * 32];
#pragma unroll
    for (int i = 0; i < 4; i++)
#pragma unroll
      for (int j = 0; j < 4; j++)
        acc[i][j] = __builtin_amdgcn_mfma_f32_16x16x32_bf16(af[i], bfr[j], acc[i][j], 0, 0, 0);
  }

  const int rbase = m0 + wr + (lane >> 4) * 4;
  const int cbase = n0 + wc + (lane & 15);
#pragma unroll
  for (int i = 0; i < 4; i++) {
#pragma unroll
    for (int j = 0; j < 4; j++) {
      const int gn = cbase + j * 16;
      const float bv = bias[gn];
#pragma unroll
      for (int jj = 0; jj < 4; jj++) {
        const int gm = rbase + i * 16 + jj;
        const float val = acc[i][j][jj] + bv;
        if (MODE == 0) {
          const int sel = gn >> 10, cc = gn & 1023;
          const int h = cc >> 6, dd = cc & 63;
          const int bb = gm >> 11, t = gm & 2047;
          ushort* dst = (sel == 0) ? oK : (sel == 1) ? oQ : oV;
          dst[((size_t)((bb * NHEAD + h) * TSEQ + t)) * DK + dd] = f2bf(val);
        } else {
          oF[(size_t)gm * N + gn] = val;
        }
      }
    }
  }
}

// ---------- causal flash attention: 1 block = 1 head x 64 Q-rows ----------
// 1024 blocks (4/CU), K/V double-buffered, 1 raw barrier per KV tile (T3 min recipe)
__global__ __launch_bounds__(256, 4)
void attn_kernel(const ushort* __restrict__ Qb, const ushort* __restrict__ Kb,
                 const ushort* __restrict__ Vtb, ushort* __restrict__ O) {
  __shared__ ushort Ks[2][64 * 64];    // [s][dk], XOR-swizzled 16B blocks, dbuf
  __shared__ ushort Vs[2][64 * 64];    // [dk][s], XOR-swizzled, dbuf
  __shared__ ushort Ps[4][16 * 64];    // per-wave P tile, XOR-swizzled

  // XCD-grouped mapping: blocks of head h land on XCD h&7 (4 heads/XCD L2);
  // qi descending = LPT within each XCD.
  const int bid = blockIdx.x;
  const int xcd = bid & 7, jj_ = bid >> 3;
  const int bh = xcd + 8 * (jj_ >> 5);
  const int qi = 31 - (jj_ & 31);
  const int q0 = qi * 64;
  const int bb = bh >> 4, h = bh & 15;
  const int tid = threadIdx.x, w = tid >> 6, lane = tid & 63;
  const int l15 = lane & 15, l4 = lane >> 4;

  // Q fragments (16 rows per wave) live in registers for the whole block
  const ushort* Qp = Qb + ((size_t)bh * TSEQ + q0 + w * 16) * DK;
  bf16x8 qf[2];
#pragma unroll
  for (int c = 0; c < 2; c++)
    qf[c] = *(const bf16x8*)(Qp + l15 * DK + c * 32 + l4 * 8);

  f32x4 oacc[4];
  float mrun[4], lrun[4];
#pragma unroll
  for (int n = 0; n < 4; n++) oacc[n] = (f32x4){0.f, 0.f, 0.f, 0.f};
#pragma unroll
  for (int r = 0; r < 4; r++) { mrun[r] = -INFINITY; lrun[r] = 0.f; }

  // staging: linear LDS dest + inverse-swizzled global source (rule #21)
  const int Bl0 = w * 128 + lane, Bl1 = Bl0 + 64;
  const int sr0 = Bl0 >> 3, sc0 = ((Bl0 & 7) ^ (sr0 & 7)) * 8;
  const int sr1 = Bl1 >> 3, sc1 = ((Bl1 & 7) ^ (sr1 & 7)) * 8;
  const ushort* Kp0 = Kb  + (size_t)bh * TSEQ * DK + sr0 * DK + sc0;
  const ushort* Kp1 = Kb  + (size_t)bh * TSEQ * DK + sr1 * DK + sc1;
  const ushort* Vp0 = Vtb + (size_t)bh * DK * TSEQ + sr0 * TSEQ + sc0;
  const ushort* Vp1 = Vtb + (size_t)bh * DK * TSEQ + sr1 * TSEQ + sc1;

  ushort* Pw = &Ps[w][0];
  const int nt = qi + 1;

  // prologue: stage tile 0 into buf 0, drain, barrier
  gload_lds16(Kp0, &Ks[0][Bl0 * 8]);
  gload_lds16(Kp1, &Ks[0][Bl1 * 8]);
  gload_lds16(Vp0, &Vs[0][Bl0 * 8]);
  gload_lds16(Vp1, &Vs[0][Bl1 * 8]);
  asm volatile("s_waitcnt vmcnt(0)" ::: "memory");
  __builtin_amdgcn_s_barrier();

  for (int ti = 0; ti < nt; ti++) {
    const int s0 = ti * 64, cur = ti & 1;

    // issue next tile's loads into the other buffer (overlap with compute)
    if (ti + 1 < nt) {
      const int sn = (ti + 1) * 64, nb = cur ^ 1;
      gload_lds16(Kp0 + sn * DK, &Ks[nb][Bl0 * 8]);
      gload_lds16(Kp1 + sn * DK, &Ks[nb][Bl1 * 8]);
      gload_lds16(Vp0 + sn, &Vs[nb][Bl0 * 8]);
      gload_lds16(Vp1 + sn, &Vs[nb][Bl1 * 8]);
    }

    // S = Q K^T
    f32x4 s[4];
    __builtin_amdgcn_s_setprio(1);
#pragma unroll
    for (int n = 0; n < 4; n++) {
      const int krow = n * 16 + l15;
      const int sw = (krow & 7) << 4;
      bf16x8 kf0 = *(const bf16x8*)((const char*)&Ks[cur][0] + krow * 128 + ((l4 * 16) ^ sw));
      bf16x8 kf1 = *(const bf16x8*)((const char*)&Ks[cur][0] + krow * 128 + ((64 + l4 * 16) ^ sw));
      f32x4 z = (f32x4){0.f, 0.f, 0.f, 0.f};
      z = __builtin_amdgcn_mfma_f32_16x16x32_bf16(qf[0], kf0, z, 0, 0, 0);
      z = __builtin_amdgcn_mfma_f32_16x16x32_bf16(qf[1], kf1, z, 0, 0, 0);
      s[n] = z;
    }
    __builtin_amdgcn_s_setprio(0);

    const bool need_mask = (s0 >= q0);
    // online softmax (fp32); row r lives in the 16 l15-lanes -> shfl_xor reduce
#pragma unroll
    for (int r = 0; r < 4; r++) {
      const int row = q0 + w * 16 + l4 * 4 + r;
      float v0 = s[0][r] * 0.125f, v1 = s[1][r] * 0.125f;
      float v2 = s[2][r] * 0.125f, v3 = s[3][r] * 0.125f;
      if (need_mask) {
        if (s0 +  0 + l15 > row) v0 = -INFINITY;
        if (s0 + 16 + l15 > row) v1 = -INFINITY;
        if (s0 + 32 + l15 > row) v2 = -INFINITY;
        if (s0 + 48 + l15 > row) v3 = -INFINITY;
      }
      float tm = fmaxf(fmaxf(v0, v1), fmaxf(v2, v3));
      tm = fmaxf(tm, __shfl_xor(tm, 1));
      tm = fmaxf(tm, __shfl_xor(tm, 2));
      tm = fmaxf(tm, __shfl_xor(tm, 4));
      tm = fmaxf(tm, __shfl_xor(tm, 8));
      const float nm  = fmaxf(mrun[r], tm);
      const float scl = __expf(mrun[r] - nm);
      mrun[r] = nm;
      v0 = __expf(v0 - nm); v1 = __expf(v1 - nm);
      v2 = __expf(v2 - nm); v3 = __expf(v3 - nm);
      float rs = v0 + v1 + v2 + v3;
      rs += __shfl_xor(rs, 1); rs += __shfl_xor(rs, 2);
      rs += __shfl_xor(rs, 4); rs += __shfl_xor(rs, 8);
      lrun[r] = lrun[r] * scl + rs;
      s[0][r] = v0; s[1][r] = v1; s[2][r] = v2; s[3][r] = v3;
      oacc[0][r] *= scl; oacc[1][r] *= scl;
      oacc[2][r] *= scl; oacc[3][r] *= scl;
    }

    // C-layout P -> A-layout fragments via per-wave swizzled LDS tile
#pragma unroll
    for (int r = 0; r < 4; r++) {
      const int prow = l4 * 4 + r;
      const int sw = (prow & 7) << 4;
      char* rp = (char*)Pw + prow * 128;
#pragma unroll
      for (int n = 0; n < 4; n++) {
        const int cb = (n * 16 + l15) * 2;
        *(ushort*)(rp + (cb ^ sw)) = f2bf(s[n][r]);
      }
    }

    bf16x8 vf[4][2];
#pragma unroll
    for (int n = 0; n < 4; n++) {
      const int vrow = n * 16 + l15;
      const int sw = (vrow & 7) << 4;
      vf[n][0] = *(const bf16x8*)((const char*)&Vs[cur][0] + vrow * 128 + ((l4 * 16) ^ sw));
      vf[n][1] = *(const bf16x8*)((const char*)&Vs[cur][0] + vrow * 128 + ((64 + l4 * 16) ^ sw));
    }
    {
      const int prow = l15;
      const int sw = (prow & 7) << 4;
      bf16x8 pf0 = *(const bf16x8*)((const char*)Pw + prow * 128 + ((l4 * 16) ^ sw));
      bf16x8 pf1 = *(const bf16x8*)((const char*)Pw + prow * 128 + ((64 + l4 * 16) ^ sw));
      __builtin_amdgcn_s_setprio(1);
#pragma unroll
      for (int n = 0; n < 4; n++) {
        oacc[n] = __builtin_amdgcn_mfma_f32_16x16x32_bf16(pf0, vf[n][0], oacc[n], 0, 0, 0);
        oacc[n] = __builtin_amdgcn_mfma_f32_16x16x32_bf16(pf1, vf[n][1], oacc[n], 0, 0, 0);
      }
      __builtin_amdgcn_s_setprio(0);
    }

    // drain next-tile loads (overlapped with the compute above), single barrier
    asm volatile("s_waitcnt vmcnt(0)" ::: "memory");
    __builtin_amdgcn_s_barrier();
  }

  // normalize + store attn output as bf16 in [B][T][H*dk]
#pragma unroll
  for (int r = 0; r < 4; r++) {
    const float inv = 1.f / lrun[r];
    const int t = q0 + w * 16 + l4 * 4 + r;
    ushort* orow = O + ((size_t)bb * TSEQ + t) * DMODEL + h * DK;
#pragma unroll
    for (int n = 0; n < 4; n++)
      orow[n * 16 + l15] = f2bf(oacc[n][r] * inv);
  }
}

extern "C" void kernel_launch(void* const* d_in, const int* in_sizes, int n_in,
                              void* d_out, int out_size, void* d_ws, size_t ws_size,
                              hipStream_t stream) {
  (void)in_sizes; (void)n_in; (void)out_size; (void)ws_size;
  const float* x    = (const float*)d_in[0];
  const float* Wkqv = (const float*)d_in[1];
  const float* bkqv = (const float*)d_in[2];
  const float* Wo   = (const float*)d_in[3];
  const float* bo   = (const float*)d_in[4];
  float* out = (float*)d_out;

  char* ws = (char*)d_ws;
  const size_t MB = 1024 * 1024;
  ushort* x_bf   = (ushort*)(ws + 0);        //  8 MB [4096][1024]
  ushort* wkqv_t = (ushort*)(ws + 8 * MB);   //  6 MB [3072][1024]
  ushort* wo_t   = (ushort*)(ws + 14 * MB);  //  2 MB [1024][1024]
  ushort* Kbuf   = (ushort*)(ws + 16 * MB);  //  8 MB [32][2048][64]
  ushort* Qbuf   = (ushort*)(ws + 24 * MB);  //  8 MB
  ushort* Vbuf   = (ushort*)(ws + 32 * MB);  //  8 MB
  ushort* Vtbuf  = (ushort*)(ws + 40 * MB);  //  8 MB [32][64][2048]
  ushort* AObuf  = (ushort*)(ws + 48 * MB);  //  8 MB [4096][1024]

  cvt_bf16_kernel<<<2048, 256, 0, stream>>>(x, x_bf, MTOT * DMODEL);
  transpose_cvt_kernel<<<dim3(3072 / 64, 1024 / 64), 256, 0, stream>>>(Wkqv, wkqv_t, 1024, 3072);
  transpose_cvt_kernel<<<dim3(1024 / 64, 1024 / 64), 256, 0, stream>>>(Wo, wo_t, 1024, 1024);
  gemm_bt_kernel<0><<<dim3(3072 / 128, 4096 / 128), 256, 0, stream>>>(
      x_bf, wkqv_t, bkqv, Kbuf, Qbuf, Vbuf, nullptr, 3072, 1024);
  transpose_v_kernel<<<dim3(TSEQ / 64, 32), 256, 0, stream>>>(Vbuf, Vtbuf);
  attn_kernel<<<1024, 256, 0, stream>>>(Qbuf, Kbuf, Vtbuf, AObuf);
  gemm_bt_kernel<1><<<dim3(1024 / 128, 4096 / 128), 256, 0, stream>>>(
      AObuf, wo_t, bo, nullptr, nullptr, nullptr, out, 1024, 1024);
}

// Round 4
// 217.883 us; speedup vs baseline: 1.2899x; 1.1744x over previous
//
#include <hip/hip_runtime.h>
#include <hip/hip_bf16.h>
#include <stdint.h>
#include <math.h>

using bf16x8 = __attribute__((ext_vector_type(8))) short;
using f32x4  = __attribute__((ext_vector_type(4))) float;
using f32x16 = __attribute__((ext_vector_type(16))) float;

#define NHEAD  16
#define DK     64
#define TSEQ   2048
#define DMODEL 1024
#define MTOT   4096   // B*T

// 0.125 (1/sqrt(dk)) * log2(e): folded into Q at the KQV epilogue so the
// flash softmax uses bare exp2.
#define QSCALE 0.18033688011112042f

static __device__ __forceinline__ ushort f2bf(float f) {
  union { float f; uint32_t u; } v; v.f = f;
  return (ushort)((v.u + 0x7FFFu + ((v.u >> 16) & 1u)) >> 16);   // RNE
}

static __device__ __forceinline__ uint32_t cvtpk_bf16(float lo, float hi) {
  uint32_t r;
  asm("v_cvt_pk_bf16_f32 %0, %1, %2" : "=v"(r) : "v"(lo), "v"(hi));
  return r;
}

static __device__ __forceinline__ void gload_lds16(const ushort* g, ushort* l) {
  typedef __attribute__((address_space(1))) const uint32_t gu32;
  typedef __attribute__((address_space(3))) uint32_t lu32;
  __builtin_amdgcn_global_load_lds((gu32*)g, (lu32*)l, 16, 0, 0);
}

// ---------- f32 -> bf16 elementwise (vectorized, G13) ----------
__global__ void cvt_bf16_kernel(const float* __restrict__ in, ushort* __restrict__ out, int n) {
  int i = (blockIdx.x * 256 + threadIdx.x) * 8;
  const int stride = gridDim.x * 256 * 8;
  for (; i < n; i += stride) {
    const float4* p = (const float4*)(in + i);
    float4 a = p[0], b = p[1];
    bf16x8 v;
    v[0]=(short)f2bf(a.x); v[1]=(short)f2bf(a.y); v[2]=(short)f2bf(a.z); v[3]=(short)f2bf(a.w);
    v[4]=(short)f2bf(b.x); v[5]=(short)f2bf(b.y); v[6]=(short)f2bf(b.z); v[7]=(short)f2bf(b.w);
    *(bf16x8*)(out + i) = v;
  }
}

// ---------- W[K][N] f32  ->  Wt[N][K] bf16 (LDS-tiled transpose) ----------
__global__ __launch_bounds__(256) void transpose_cvt_kernel(const float* __restrict__ W,
                                                            ushort* __restrict__ Wt, int K, int N) {
  __shared__ ushort tl[64][66];
  const int n0 = blockIdx.x * 64, k0 = blockIdx.y * 64;
  const int c = threadIdx.x & 63, r0 = threadIdx.x >> 6;
#pragma unroll
  for (int i = 0; i < 64; i += 4)
    tl[i + r0][c] = f2bf(W[(size_t)(k0 + i + r0) * N + n0 + c]);
  __syncthreads();
#pragma unroll
  for (int i = 0; i < 64; i += 4)
    Wt[(size_t)(n0 + i + r0) * K + k0 + c] = tl[c][i + r0];
}

// ---------- V[bh][T][64] bf16 -> Vt[bh][64][T] bf16 ----------
__global__ __launch_bounds__(256) void transpose_v_kernel(const ushort* __restrict__ V,
                                                          ushort* __restrict__ Vt) {
  __shared__ ushort tl[64][66];
  const int bh = blockIdx.y, t0 = blockIdx.x * 64;
  const int c = threadIdx.x & 63, r0 = threadIdx.x >> 6;
  const ushort* Vb = V + (size_t)bh * TSEQ * DK;
  ushort* Vtb = Vt + (size_t)bh * DK * TSEQ;
#pragma unroll
  for (int i = 0; i < 64; i += 4)
    tl[i + r0][c] = Vb[(size_t)(t0 + i + r0) * DK + c];
  __syncthreads();
#pragma unroll
  for (int i = 0; i < 64; i += 4)
    Vtb[(size_t)(i + r0) * TSEQ + t0 + c] = tl[c][i + r0];
}

// ---------- m97-style bf16 GEMM, C = A[M][K] * Bt[N][K]^T + bias ----------
// MODE 0: scatters K,Q,V (bf16) into [B,H,T,dk], Q pre-scaled by QSCALE;
// MODE 1: fp32 out [M][N]
template <int MODE>
__global__ __launch_bounds__(256, 2)
void gemm_bt_kernel(const ushort* __restrict__ A, const ushort* __restrict__ Bt,
                    const float* __restrict__ bias,
                    ushort* __restrict__ oK, ushort* __restrict__ oQ, ushort* __restrict__ oV,
                    float* __restrict__ oF, int N, int K) {
  __shared__ ushort As[128 * 32];
  __shared__ ushort Bs[128 * 32];
  const int tid = threadIdx.x;
  const int w = tid >> 6, lane = tid & 63;
  const int m0 = blockIdx.y * 128, n0 = blockIdx.x * 128;
  const int wr = (w >> 1) * 64, wc = (w & 1) * 64;

  const int e0 = ((w * 2 + 0) * 64 + lane) * 8;
  const int e1 = ((w * 2 + 1) * 64 + lane) * 8;
  const ushort* pA0 = A  + (size_t)(m0 + (e0 >> 5)) * K + (e0 & 31);
  const ushort* pA1 = A  + (size_t)(m0 + (e1 >> 5)) * K + (e1 & 31);
  const ushort* pB0 = Bt + (size_t)(n0 + (e0 >> 5)) * K + (e0 & 31);
  const ushort* pB1 = Bt + (size_t)(n0 + (e1 >> 5)) * K + (e1 & 31);

  f32x4 acc[4][4];
#pragma unroll
  for (int i = 0; i < 4; i++)
#pragma unroll
    for (int j = 0; j < 4; j++) acc[i][j] = (f32x4){0.f, 0.f, 0.f, 0.f};

  const int aro = (wr + (lane & 15)) * 32 + (lane >> 4) * 8;
  const int bro = (wc + (lane & 15)) * 32 + (lane >> 4) * 8;

  for (int k0 = 0; k0 < K; k0 += 32) {
    __syncthreads();
    gload_lds16(pA0 + k0, &As[e0]);
    gload_lds16(pA1 + k0, &As[e1]);
    gload_lds16(pB0 + k0, &Bs[e0]);
    gload_lds16(pB1 + k0, &Bs[e1]);
    __syncthreads();
    bf16x8 af[4], bfr[4];
#pragma unroll
    for (int i = 0; i < 4; i++) af[i]  = *(const bf16x8*)&As[aro + i * 16 * 32];
#pragma unroll
    for (int j = 0; j < 4; j++) bfr[j] = *(const bf16x8*)&Bs[bro + j * 16 * 32];
#pragma unroll
    for (int i = 0; i < 4; i++)
#pragma unroll
      for (int j = 0; j < 4; j++)
        acc[i][j] = __builtin_amdgcn_mfma_f32_16x16x32_bf16(af[i], bfr[j], acc[i][j], 0, 0, 0);
  }

  const int rbase = m0 + wr + (lane >> 4) * 4;
  const int cbase = n0 + wc + (lane & 15);
#pragma unroll
  for (int i = 0; i < 4; i++) {
#pragma unroll
    for (int j = 0; j < 4; j++) {
      const int gn = cbase + j * 16;
      const float bv = bias[gn];
#pragma unroll
      for (int jj = 0; jj < 4; jj++) {
        const int gm = rbase + i * 16 + jj;
        float val = acc[i][j][jj] + bv;
        if (MODE == 0) {
          const int sel = gn >> 10, cc = gn & 1023;
          const int hh = cc >> 6, dd = cc & 63;
          const int bbx = gm >> 11, t = gm & 2047;
          if (sel == 1) val *= QSCALE;   // pre-scale Q (exact-ish, before bf16 round)
          ushort* dst = (sel == 0) ? oK : (sel == 1) ? oQ : oV;
          dst[((size_t)((bbx * NHEAD + hh) * TSEQ + t)) * DK + dd] = f2bf(val);
        } else {
          oF[(size_t)gm * N + gn] = val;
        }
      }
    }
  }
}

// ---------- causal flash attention, swapped-QK^T (m214 structure) ----------
// 512 blocks = 32 bh x 4 q-tiles of 128 rows; 4 waves x 32 q-rows each.
// S = mfma(K, Q) -> lane&31 owns one q-row; softmax fully in-register;
// PV = mfma(Vt, P) -> output also keyed by lane&31 = q.
__global__ __launch_bounds__(256, 2)
void attn_kernel(const ushort* __restrict__ Qb, const ushort* __restrict__ Kb,
                 const ushort* __restrict__ Vtb, ushort* __restrict__ O) {
  __shared__ ushort Ks[2][64 * 64];    // [kv][dk], XOR-swizzled 16B blocks, dbuf
  __shared__ ushort Vs[2][64 * 64];    // [d][kv], XOR-swizzled, dbuf

  // XCD-grouped mapping (4 heads per XCD L2) + LPT (qi descending)
  const int bid = blockIdx.x;
  const int xcd = bid & 7, j = bid >> 3;            // j in [0,64)
  const int bh = xcd + 8 * (j >> 4);                // 4 head-groups per xcd
  const int qi = 15 - (j & 15);
  const int q0 = qi * 128;
  const int bb = bh >> 4, hd = bh & 15;
  const int tid = threadIdx.x, w = tid >> 6, lane = tid & 63;
  const int l31 = lane & 31, h = lane >> 5;         // h = wave half
  const int qrow = q0 + w * 32 + l31;               // this lane's q-row

  // Q fragments: B-operand of 32x32x16 -> B[n=q=l31][k=(h*8+j)], 4 dk-slices
  const ushort* Qp = Qb + ((size_t)bh * TSEQ + qrow) * DK;
  bf16x8 qf[4];
#pragma unroll
  for (int c = 0; c < 4; c++)
    qf[c] = *(const bf16x8*)(Qp + c * 16 + h * 8);

  f32x16 oacc0, oacc1;                 // out[d = dh*32 + (r&3)+8*(r>>2)+4h][q=l31]
#pragma unroll
  for (int r = 0; r < 16; r++) { oacc0[r] = 0.f; oacc1[r] = 0.f; }
  float mrun = -INFINITY, lrun = 0.f;  // per-lane = per-q-row (both halves agree)

  // staging: linear LDS dest + inverse-swizzled global source (rule #21)
  const int Bl0 = w * 128 + lane, Bl1 = Bl0 + 64;
  const int sr0 = Bl0 >> 3, sc0 = ((Bl0 & 7) ^ (sr0 & 7)) * 8;
  const int sr1 = Bl1 >> 3, sc1 = ((Bl1 & 7) ^ (sr1 & 7)) * 8;
  const ushort* Kp0 = Kb  + (size_t)bh * TSEQ * DK + sr0 * DK + sc0;
  const ushort* Kp1 = Kb  + (size_t)bh * TSEQ * DK + sr1 * DK + sc1;
  const ushort* Vp0 = Vtb + (size_t)bh * DK * TSEQ + sr0 * TSEQ + sc0;
  const ushort* Vp1 = Vtb + (size_t)bh * DK * TSEQ + sr1 * TSEQ + sc1;

  const int nt = 2 * qi + 2;

  // prologue: stage tile 0 into buf 0, drain, barrier
  gload_lds16(Kp0, &Ks[0][Bl0 * 8]);
  gload_lds16(Kp1, &Ks[0][Bl1 * 8]);
  gload_lds16(Vp0, &Vs[0][Bl0 * 8]);
  gload_lds16(Vp1, &Vs[0][Bl1 * 8]);
  asm volatile("s_waitcnt vmcnt(0)" ::: "memory");
  __builtin_amdgcn_s_barrier();

  for (int ti = 0; ti < nt; ti++) {
    const int s0 = ti * 64, cur = ti & 1;

    if (ti + 1 < nt) {
      const int sn = (ti + 1) * 64, nb = cur ^ 1;
      gload_lds16(Kp0 + sn * DK, &Ks[nb][Bl0 * 8]);
      gload_lds16(Kp1 + sn * DK, &Ks[nb][Bl1 * 8]);
      gload_lds16(Vp0 + sn, &Vs[nb][Bl0 * 8]);
      gload_lds16(Vp1 + sn, &Vs[nb][Bl1 * 8]);
    }

    const bool active = (s0 <= q0 + w * 32 + 31);   // wave-uniform
    if (active) {
      // ---- S = K x Q : D[col=q=l31][row=kv_local] ----
      f32x16 ps0, ps1;
#pragma unroll
      for (int r = 0; r < 16; r++) { ps0[r] = 0.f; ps1[r] = 0.f; }
      const char* Kbase = (const char*)&Ks[cur][0];
      __builtin_amdgcn_s_setprio(1);
#pragma unroll
      for (int c = 0; c < 4; c++) {
        const int r0 = l31, r1 = 32 + l31;
        bf16x8 kf0 = *(const bf16x8*)(Kbase + r0 * 128 + ((c * 32 + h * 16) ^ ((r0 & 7) << 4)));
        bf16x8 kf1 = *(const bf16x8*)(Kbase + r1 * 128 + ((c * 32 + h * 16) ^ ((r1 & 7) << 4)));
        ps0 = __builtin_amdgcn_mfma_f32_32x32x16_bf16(kf0, qf[c], ps0, 0, 0, 0);
        ps1 = __builtin_amdgcn_mfma_f32_32x32x16_bf16(kf1, qf[c], ps1, 0, 0, 0);
      }
      __builtin_amdgcn_s_setprio(0);

      // ---- mask (boundary tiles only) ----
      if (s0 + 63 > q0 + w * 32) {
#pragma unroll
        for (int r = 0; r < 16; r++) {
          const int kv0 = s0 + (r & 3) + 8 * (r >> 2) + 4 * h;
          if (kv0 > qrow)      ps0[r] = -INFINITY;
          if (kv0 + 32 > qrow) ps1[r] = -INFINITY;
        }
      }

      // ---- in-register row max (lane = q-row) ----
      float pm = ps0[0];
#pragma unroll
      for (int r = 1; r < 16; r++) pm = fmaxf(pm, ps0[r]);
#pragma unroll
      for (int r = 0; r < 16; r++) pm = fmaxf(pm, ps1[r]);
      pm = fmaxf(pm, __shfl_xor(pm, 32));

      // ---- defer-max (T13): rescale only when max grew > 8 (log2 units) ----
      if (!__all(pm <= mrun + 8.0f)) {
        const float nm = fmaxf(mrun, pm);
        const float scl = exp2f(mrun - nm);
        lrun *= scl;
#pragma unroll
        for (int r = 0; r < 16; r++) { oacc0[r] *= scl; oacc1[r] *= scl; }
        mrun = nm;
      }

      // ---- exp2 + row sum ----
#pragma unroll
      for (int r = 0; r < 16; r++) ps0[r] = exp2f(ps0[r] - mrun);
#pragma unroll
      for (int r = 0; r < 16; r++) ps1[r] = exp2f(ps1[r] - mrun);
      float rs = 0.f;
#pragma unroll
      for (int r = 0; r < 16; r++) rs += ps0[r] + ps1[r];
      rs += __shfl_xor(rs, 32);
      lrun += rs;

      // ---- pack P to bf16 words: w0[s][a]=(b0,b1-of-half), w1[s][a]=(b2,b3) ----
      uint32_t w0[2][4], w1[2][4];
#pragma unroll
      for (int a = 0; a < 4; a++) {
        w0[0][a] = cvtpk_bf16(ps0[4 * a + 0], ps0[4 * a + 1]);
        w1[0][a] = cvtpk_bf16(ps0[4 * a + 2], ps0[4 * a + 3]);
        w0[1][a] = cvtpk_bf16(ps1[4 * a + 0], ps1[4 * a + 1]);
        w1[1][a] = cvtpk_bf16(ps1[4 * a + 2], ps1[4 * a + 3]);
      }

      // ---- PV: for each kv-16-slice t=2s+u, build P B-frag via half exchange,
      //      then oacc[dh] = mfma(A=Vt, B=P, oacc[dh]) ----
      const char* Vbase = (const char*)&Vs[cur][0];
#pragma unroll
      for (int s = 0; s < 2; s++) {
#pragma unroll
        for (int u = 0; u < 2; u++) {
          const int t = 2 * s + u;
          const uint32_t sw0 = h ? w0[s][2 * u] : w0[s][2 * u + 1];
          const uint32_t sw1 = h ? w1[s][2 * u] : w1[s][2 * u + 1];
          const uint32_t rx0 = (uint32_t)__shfl_xor((int)sw0, 32);
          const uint32_t rx1 = (uint32_t)__shfl_xor((int)sw1, 32);
          int4 pw;
          pw.x = h ? (int)rx0 : (int)w0[s][2 * u];
          pw.y = h ? (int)rx1 : (int)w1[s][2 * u];
          pw.z = h ? (int)w0[s][2 * u + 1] : (int)rx0;
          pw.w = h ? (int)w1[s][2 * u + 1] : (int)rx1;
          const bf16x8 pf = __builtin_bit_cast(bf16x8, pw);

          const int vr0 = l31, vr1 = 32 + l31;
          bf16x8 vf0 = *(const bf16x8*)(Vbase + vr0 * 128 + ((t * 32 + h * 16) ^ ((vr0 & 7) << 4)));
          bf16x8 vf1 = *(const bf16x8*)(Vbase + vr1 * 128 + ((t * 32 + h * 16) ^ ((vr1 & 7) << 4)));
          __builtin_amdgcn_s_setprio(1);
          oacc0 = __builtin_amdgcn_mfma_f32_32x32x16_bf16(vf0, pf, oacc0, 0, 0, 0);
          oacc1 = __builtin_amdgcn_mfma_f32_32x32x16_bf16(vf1, pf, oacc1, 0, 0, 0);
          __builtin_amdgcn_s_setprio(0);
        }
      }
    }

    asm volatile("s_waitcnt vmcnt(0)" ::: "memory");
    __builtin_amdgcn_s_barrier();
  }

  // ---- normalize + store: lane = q-row; d = dh*32 + (r&3)+8*(r>>2)+4h ----
  const float inv = 1.f / lrun;
  ushort* orow = O + ((size_t)bb * TSEQ + qrow) * DMODEL + hd * DK;
#pragma unroll
  for (int r = 0; r < 16; r += 2) {
    const int d0 = (r & 3) + 8 * (r >> 2) + 4 * h;        // even, d1 = d0+1
    const uint32_t v0 = (uint32_t)f2bf(oacc0[r] * inv) | ((uint32_t)f2bf(oacc0[r + 1] * inv) << 16);
    const uint32_t v1 = (uint32_t)f2bf(oacc1[r] * inv) | ((uint32_t)f2bf(oacc1[r + 1] * inv) << 16);
    *(uint32_t*)(orow + d0)      = v0;
    *(uint32_t*)(orow + 32 + d0) = v1;
  }
}

extern "C" void kernel_launch(void* const* d_in, const int* in_sizes, int n_in,
                              void* d_out, int out_size, void* d_ws, size_t ws_size,
                              hipStream_t stream) {
  (void)in_sizes; (void)n_in; (void)out_size; (void)ws_size;
  const float* x    = (const float*)d_in[0];
  const float* Wkqv = (const float*)d_in[1];
  const float* bkqv = (const float*)d_in[2];
  const float* Wo   = (const float*)d_in[3];
  const float* bo   = (const float*)d_in[4];
  float* out = (float*)d_out;

  char* ws = (char*)d_ws;
  const size_t MB = 1024 * 1024;
  ushort* x_bf   = (ushort*)(ws + 0);        //  8 MB [4096][1024]
  ushort* wkqv_t = (ushort*)(ws + 8 * MB);   //  6 MB [3072][1024]
  ushort* wo_t   = (ushort*)(ws + 14 * MB);  //  2 MB [1024][1024]
  ushort* Kbuf   = (ushort*)(ws + 16 * MB);  //  8 MB [32][2048][64]
  ushort* Qbuf   = (ushort*)(ws + 24 * MB);  //  8 MB (pre-scaled by QSCALE)
  ushort* Vbuf   = (ushort*)(ws + 32 * MB);  //  8 MB
  ushort* Vtbuf  = (ushort*)(ws + 40 * MB);  //  8 MB [32][64][2048]
  ushort* AObuf  = (ushort*)(ws + 48 * MB);  //  8 MB [4096][1024]

  cvt_bf16_kernel<<<2048, 256, 0, stream>>>(x, x_bf, MTOT * DMODEL);
  transpose_cvt_kernel<<<dim3(3072 / 64, 1024 / 64), 256, 0, stream>>>(Wkqv, wkqv_t, 1024, 3072);
  transpose_cvt_kernel<<<dim3(1024 / 64, 1024 / 64), 256, 0, stream>>>(Wo, wo_t, 1024, 1024);
  gemm_bt_kernel<0><<<dim3(3072 / 128, 4096 / 128), 256, 0, stream>>>(
      x_bf, wkqv_t, bkqv, Kbuf, Qbuf, Vbuf, nullptr, 3072, 1024);
  transpose_v_kernel<<<dim3(TSEQ / 64, 32), 256, 0, stream>>>(Vbuf, Vtbuf);
  attn_kernel<<<512, 256, 0, stream>>>(Qbuf, Kbuf, Vtbuf, AObuf);
  gemm_bt_kernel<1><<<dim3(1024 / 128, 4096 / 128), 256, 0, stream>>>(
      AObuf, wo_t, bo, nullptr, nullptr, nullptr, out, 1024, 1024);
}

// Round 5
// 216.679 us; speedup vs baseline: 1.2971x; 1.0056x over previous
//
#include <hip/hip_runtime.h>
#include <hip/hip_bf16.h>
#include <stdint.h>
#include <math.h>

using bf16x8 = __attribute__((ext_vector_type(8))) short;
using f32x4  = __attribute__((ext_vector_type(4))) float;
using f32x16 = __attribute__((ext_vector_type(16))) float;

#define NHEAD  16
#define DK     64
#define TSEQ   2048
#define DMODEL 1024
#define MTOT   4096   // B*T

// 0.125 (1/sqrt(dk)) * log2(e): folded into Q at the KQV epilogue so the
// flash softmax uses bare exp2.
#define QSCALE 0.18033688011112042f

static __device__ __forceinline__ ushort f2bf(float f) {
  union { float f; uint32_t u; } v; v.f = f;
  return (ushort)((v.u + 0x7FFFu + ((v.u >> 16) & 1u)) >> 16);   // RNE
}

static __device__ __forceinline__ float bf2f(ushort u) {
  union { uint32_t u; float f; } v; v.u = ((uint32_t)u) << 16;
  return v.f;
}

static __device__ __forceinline__ uint32_t cvtpk_bf16(float lo, float hi) {
  uint32_t r;
  asm("v_cvt_pk_bf16_f32 %0, %1, %2" : "=v"(r) : "v"(lo), "v"(hi));
  return r;
}

static __device__ __forceinline__ void gload_lds16(const ushort* g, ushort* l) {
  typedef __attribute__((address_space(1))) const uint32_t gu32;
  typedef __attribute__((address_space(3))) uint32_t lu32;
  __builtin_amdgcn_global_load_lds((gu32*)g, (lu32*)l, 16, 0, 0);
}

// ---------- f32 -> bf16 elementwise (vectorized, G13) ----------
__global__ void cvt_bf16_kernel(const float* __restrict__ in, ushort* __restrict__ out, int n) {
  int i = (blockIdx.x * 256 + threadIdx.x) * 8;
  const int stride = gridDim.x * 256 * 8;
  for (; i < n; i += stride) {
    const float4* p = (const float4*)(in + i);
    float4 a = p[0], b = p[1];
    bf16x8 v;
    v[0]=(short)f2bf(a.x); v[1]=(short)f2bf(a.y); v[2]=(short)f2bf(a.z); v[3]=(short)f2bf(a.w);
    v[4]=(short)f2bf(b.x); v[5]=(short)f2bf(b.y); v[6]=(short)f2bf(b.z); v[7]=(short)f2bf(b.w);
    *(bf16x8*)(out + i) = v;
  }
}

// ---------- W[K][N] f32  ->  Wt[N][K] bf16 (LDS-tiled transpose) ----------
__global__ __launch_bounds__(256) void transpose_cvt_kernel(const float* __restrict__ W,
                                                            ushort* __restrict__ Wt, int K, int N) {
  __shared__ ushort tl[64][66];
  const int n0 = blockIdx.x * 64, k0 = blockIdx.y * 64;
  const int c = threadIdx.x & 63, r0 = threadIdx.x >> 6;
#pragma unroll
  for (int i = 0; i < 64; i += 4)
    tl[i + r0][c] = f2bf(W[(size_t)(k0 + i + r0) * N + n0 + c]);
  __syncthreads();
#pragma unroll
  for (int i = 0; i < 64; i += 4)
    Wt[(size_t)(n0 + i + r0) * K + k0 + c] = tl[c][i + r0];
}

// ---------- V[bh][T][64] bf16 -> Vt[bh][64][T] bf16 ----------
__global__ __launch_bounds__(256) void transpose_v_kernel(const ushort* __restrict__ V,
                                                          ushort* __restrict__ Vt) {
  __shared__ ushort tl[64][66];
  const int bh = blockIdx.y, t0 = blockIdx.x * 64;
  const int c = threadIdx.x & 63, r0 = threadIdx.x >> 6;
  const ushort* Vb = V + (size_t)bh * TSEQ * DK;
  ushort* Vtb = Vt + (size_t)bh * DK * TSEQ;
#pragma unroll
  for (int i = 0; i < 64; i += 4)
    tl[i + r0][c] = Vb[(size_t)(t0 + i + r0) * DK + c];
  __syncthreads();
#pragma unroll
  for (int i = 0; i < 64; i += 4)
    Vtb[(size_t)(i + r0) * TSEQ + t0 + c] = tl[c][i + r0];
}

// ---------- m97-style bf16 GEMM, C = A[M][K] * Bt[N][K]^T + bias ----------
// MODE 0: scatters K,Q,V (bf16) into [B,H,T,dk], Q pre-scaled by QSCALE;
// MODE 1: fp32 out [M][N]
template <int MODE>
__global__ __launch_bounds__(256, 2)
void gemm_bt_kernel(const ushort* __restrict__ A, const ushort* __restrict__ Bt,
                    const float* __restrict__ bias,
                    ushort* __restrict__ oK, ushort* __restrict__ oQ, ushort* __restrict__ oV,
                    float* __restrict__ oF, int N, int K) {
  __shared__ ushort As[128 * 32];
  __shared__ ushort Bs[128 * 32];
  const int tid = threadIdx.x;
  const int w = tid >> 6, lane = tid & 63;
  const int m0 = blockIdx.y * 128, n0 = blockIdx.x * 128;
  const int wr = (w >> 1) * 64, wc = (w & 1) * 64;

  const int e0 = ((w * 2 + 0) * 64 + lane) * 8;
  const int e1 = ((w * 2 + 1) * 64 + lane) * 8;
  const ushort* pA0 = A  + (size_t)(m0 + (e0 >> 5)) * K + (e0 & 31);
  const ushort* pA1 = A  + (size_t)(m0 + (e1 >> 5)) * K + (e1 & 31);
  const ushort* pB0 = Bt + (size_t)(n0 + (e0 >> 5)) * K + (e0 & 31);
  const ushort* pB1 = Bt + (size_t)(n0 + (e1 >> 5)) * K + (e1 & 31);

  f32x4 acc[4][4];
#pragma unroll
  for (int i = 0; i < 4; i++)
#pragma unroll
    for (int j = 0; j < 4; j++) acc[i][j] = (f32x4){0.f, 0.f, 0.f, 0.f};

  const int aro = (wr + (lane & 15)) * 32 + (lane >> 4) * 8;
  const int bro = (wc + (lane & 15)) * 32 + (lane >> 4) * 8;

  for (int k0 = 0; k0 < K; k0 += 32) {
    __syncthreads();
    gload_lds16(pA0 + k0, &As[e0]);
    gload_lds16(pA1 + k0, &As[e1]);
    gload_lds16(pB0 + k0, &Bs[e0]);
    gload_lds16(pB1 + k0, &Bs[e1]);
    __syncthreads();
    bf16x8 af[4], bfr[4];
#pragma unroll
    for (int i = 0; i < 4; i++) af[i]  = *(const bf16x8*)&As[aro + i * 16 * 32];
#pragma unroll
    for (int j = 0; j < 4; j++) bfr[j] = *(const bf16x8*)&Bs[bro + j * 16 * 32];
#pragma unroll
    for (int i = 0; i < 4; i++)
#pragma unroll
      for (int j = 0; j < 4; j++)
        acc[i][j] = __builtin_amdgcn_mfma_f32_16x16x32_bf16(af[i], bfr[j], acc[i][j], 0, 0, 0);
  }

  const int rbase = m0 + wr + (lane >> 4) * 4;
  const int cbase = n0 + wc + (lane & 15);
#pragma unroll
  for (int i = 0; i < 4; i++) {
#pragma unroll
    for (int j = 0; j < 4; j++) {
      const int gn = cbase + j * 16;
      const float bv = bias[gn];
#pragma unroll
      for (int jj = 0; jj < 4; jj++) {
        const int gm = rbase + i * 16 + jj;
        float val = acc[i][j][jj] + bv;
        if (MODE == 0) {
          const int sel = gn >> 10, cc = gn & 1023;
          const int hh = cc >> 6, dd = cc & 63;
          const int bbx = gm >> 11, t = gm & 2047;
          if (sel == 1) val *= QSCALE;   // pre-scale Q (before bf16 round)
          ushort* dst = (sel == 0) ? oK : (sel == 1) ? oQ : oV;
          dst[((size_t)((bbx * NHEAD + hh) * TSEQ + t)) * DK + dd] = f2bf(val);
        } else {
          oF[(size_t)gm * N + gn] = val;
        }
      }
    }
  }
}

// ---------- causal flash attention, swapped-QK^T + split-KV ----------
// 1024 pieces = 32 bh x 16 q-tiles(128 rows) x 2 KV-halves (qi+1 tiles each).
// 4 waves x 32 q-rows; S = mfma(K,Q) -> lane owns a q-row; softmax in-register;
// PV = mfma(Vt,P). Pieces write unnormalized O (bf16) + (m,l) partials.
__global__ __launch_bounds__(256, 4)
void attn_kernel(const ushort* __restrict__ Qb, const ushort* __restrict__ Kb,
                 const ushort* __restrict__ Vtb, ushort* __restrict__ Opart,
                 float2* __restrict__ mlbuf) {
  __shared__ ushort Ks[2][64 * 64];    // [kv][dk], XOR-swizzled 16B blocks, dbuf
  __shared__ ushort Vs[2][64 * 64];    // [d][kv], XOR-swizzled, dbuf

  // XCD-grouped mapping (4 heads per XCD L2) + LPT (qi descending)
  const int bid = blockIdx.x;
  const int xcd = bid & 7, j = bid >> 3;            // j in [0,128)
  const int bh = xcd + 8 * (j >> 5);                // 4 head-groups per xcd
  const int qq = j & 31;
  const int qi = 15 - (qq >> 1);                    // LPT: big qi first
  const int half = qq & 1;
  const int q0 = qi * 128;
  const int tid = threadIdx.x, w = tid >> 6, lane = tid & 63;
  const int l31 = lane & 31, h = lane >> 5;         // h = wave half
  const int qrow = q0 + w * 32 + l31;               // this lane's q-row

  // piece KV-tile range: half 0 -> [0, qi+1), half 1 -> [qi+1, 2qi+2)
  const int t_begin = half ? (qi + 1) : 0;
  const int ntp = qi + 1;

  // Q fragments: B-operand of 32x32x16 -> B[n=q=l31][k=(h*8+j)], 4 dk-slices
  const ushort* Qp = Qb + ((size_t)bh * TSEQ + qrow) * DK;
  bf16x8 qf[4];
#pragma unroll
  for (int c = 0; c < 4; c++)
    qf[c] = *(const bf16x8*)(Qp + c * 16 + h * 8);

  f32x16 oacc0, oacc1;                 // out[d = dh*32 + (r&3)+8*(r>>2)+4h][q=l31]
#pragma unroll
  for (int r = 0; r < 16; r++) { oacc0[r] = 0.f; oacc1[r] = 0.f; }
  float mrun = -INFINITY, lrun = 0.f;  // per-lane = per-q-row (both halves agree)

  // staging: linear LDS dest + inverse-swizzled global source (rule #21)
  const int Bl0 = w * 128 + lane, Bl1 = Bl0 + 64;
  const int sr0 = Bl0 >> 3, sc0 = ((Bl0 & 7) ^ (sr0 & 7)) * 8;
  const int sr1 = Bl1 >> 3, sc1 = ((Bl1 & 7) ^ (sr1 & 7)) * 8;
  const ushort* Kp0 = Kb  + (size_t)bh * TSEQ * DK + sr0 * DK + sc0;
  const ushort* Kp1 = Kb  + (size_t)bh * TSEQ * DK + sr1 * DK + sc1;
  const ushort* Vp0 = Vtb + (size_t)bh * DK * TSEQ + sr0 * TSEQ + sc0;
  const ushort* Vp1 = Vtb + (size_t)bh * DK * TSEQ + sr1 * TSEQ + sc1;

  // prologue: stage tile t_begin into buf 0, drain, barrier
  {
    const int s0 = t_begin * 64;
    gload_lds16(Kp0 + s0 * DK, &Ks[0][Bl0 * 8]);
    gload_lds16(Kp1 + s0 * DK, &Ks[0][Bl1 * 8]);
    gload_lds16(Vp0 + s0, &Vs[0][Bl0 * 8]);
    gload_lds16(Vp1 + s0, &Vs[0][Bl1 * 8]);
  }
  asm volatile("s_waitcnt vmcnt(0)" ::: "memory");
  __builtin_amdgcn_s_barrier();

  for (int tt = 0; tt < ntp; tt++) {
    const int s0 = (t_begin + tt) * 64, cur = tt & 1;

    if (tt + 1 < ntp) {
      const int sn = (t_begin + tt + 1) * 64, nb = cur ^ 1;
      gload_lds16(Kp0 + sn * DK, &Ks[nb][Bl0 * 8]);
      gload_lds16(Kp1 + sn * DK, &Ks[nb][Bl1 * 8]);
      gload_lds16(Vp0 + sn, &Vs[nb][Bl0 * 8]);
      gload_lds16(Vp1 + sn, &Vs[nb][Bl1 * 8]);
    }

    const bool active = (s0 <= q0 + w * 32 + 31);   // wave-uniform
    if (active) {
      // ---- S = K x Q : D[col=q=l31][row=kv_local] ----
      f32x16 ps0, ps1;
#pragma unroll
      for (int r = 0; r < 16; r++) { ps0[r] = 0.f; ps1[r] = 0.f; }
      const char* Kbase = (const char*)&Ks[cur][0];
      __builtin_amdgcn_s_setprio(1);
#pragma unroll
      for (int c = 0; c < 4; c++) {
        const int r0 = l31, r1 = 32 + l31;
        bf16x8 kf0 = *(const bf16x8*)(Kbase + r0 * 128 + ((c * 32 + h * 16) ^ ((r0 & 7) << 4)));
        bf16x8 kf1 = *(const bf16x8*)(Kbase + r1 * 128 + ((c * 32 + h * 16) ^ ((r1 & 7) << 4)));
        ps0 = __builtin_amdgcn_mfma_f32_32x32x16_bf16(kf0, qf[c], ps0, 0, 0, 0);
        ps1 = __builtin_amdgcn_mfma_f32_32x32x16_bf16(kf1, qf[c], ps1, 0, 0, 0);
      }
      __builtin_amdgcn_s_setprio(0);

      // ---- mask (boundary tiles only) ----
      if (s0 + 63 > q0 + w * 32) {
#pragma unroll
        for (int r = 0; r < 16; r++) {
          const int kv0 = s0 + (r & 3) + 8 * (r >> 2) + 4 * h;
          if (kv0 > qrow)      ps0[r] = -INFINITY;
          if (kv0 + 32 > qrow) ps1[r] = -INFINITY;
        }
      }

      // ---- in-register row max (lane = q-row) ----
      float pm = ps0[0];
#pragma unroll
      for (int r = 1; r < 16; r++) pm = fmaxf(pm, ps0[r]);
#pragma unroll
      for (int r = 0; r < 16; r++) pm = fmaxf(pm, ps1[r]);
      pm = fmaxf(pm, __shfl_xor(pm, 32));

      // ---- defer-max (T13): rescale only when max grew > 8 (log2 units) ----
      if (!__all(pm <= mrun + 8.0f)) {
        const float nm = fmaxf(mrun, pm);
        const float scl = exp2f(mrun - nm);
        lrun *= scl;
#pragma unroll
        for (int r = 0; r < 16; r++) { oacc0[r] *= scl; oacc1[r] *= scl; }
        mrun = nm;
      }

      // ---- exp2 + row sum ----
#pragma unroll
      for (int r = 0; r < 16; r++) ps0[r] = exp2f(ps0[r] - mrun);
#pragma unroll
      for (int r = 0; r < 16; r++) ps1[r] = exp2f(ps1[r] - mrun);
      float rs = 0.f;
#pragma unroll
      for (int r = 0; r < 16; r++) rs += ps0[r] + ps1[r];
      rs += __shfl_xor(rs, 32);
      lrun += rs;

      // ---- pack P to bf16 words ----
      uint32_t w0[2][4], w1[2][4];
#pragma unroll
      for (int a = 0; a < 4; a++) {
        w0[0][a] = cvtpk_bf16(ps0[4 * a + 0], ps0[4 * a + 1]);
        w1[0][a] = cvtpk_bf16(ps0[4 * a + 2], ps0[4 * a + 3]);
        w0[1][a] = cvtpk_bf16(ps1[4 * a + 0], ps1[4 * a + 1]);
        w1[1][a] = cvtpk_bf16(ps1[4 * a + 2], ps1[4 * a + 3]);
      }

      // ---- PV: per kv-16-slice t=2s+u, build P B-frag via half exchange ----
      const char* Vbase = (const char*)&Vs[cur][0];
#pragma unroll
      for (int s = 0; s < 2; s++) {
#pragma unroll
        for (int u = 0; u < 2; u++) {
          const int t = 2 * s + u;
          const uint32_t sw0 = h ? w0[s][2 * u] : w0[s][2 * u + 1];
          const uint32_t sw1 = h ? w1[s][2 * u] : w1[s][2 * u + 1];
          const uint32_t rx0 = (uint32_t)__shfl_xor((int)sw0, 32);
          const uint32_t rx1 = (uint32_t)__shfl_xor((int)sw1, 32);
          int4 pw;
          pw.x = h ? (int)rx0 : (int)w0[s][2 * u];
          pw.y = h ? (int)rx1 : (int)w1[s][2 * u];
          pw.z = h ? (int)w0[s][2 * u + 1] : (int)rx0;
          pw.w = h ? (int)w1[s][2 * u + 1] : (int)rx1;
          const bf16x8 pf = __builtin_bit_cast(bf16x8, pw);

          const int vr0 = l31, vr1 = 32 + l31;
          bf16x8 vf0 = *(const bf16x8*)(Vbase + vr0 * 128 + ((t * 32 + h * 16) ^ ((vr0 & 7) << 4)));
          bf16x8 vf1 = *(const bf16x8*)(Vbase + vr1 * 128 + ((t * 32 + h * 16) ^ ((vr1 & 7) << 4)));
          __builtin_amdgcn_s_setprio(1);
          oacc0 = __builtin_amdgcn_mfma_f32_32x32x16_bf16(vf0, pf, oacc0, 0, 0, 0);
          oacc1 = __builtin_amdgcn_mfma_f32_32x32x16_bf16(vf1, pf, oacc1, 0, 0, 0);
          __builtin_amdgcn_s_setprio(0);
        }
      }
    }

    asm volatile("s_waitcnt vmcnt(0)" ::: "memory");
    __builtin_amdgcn_s_barrier();
  }

  // ---- write partials: unnormalized O (bf16) + (m, l) ----
  const size_t rowidx = ((size_t)bh * TSEQ + qrow) * 2 + half;
  ushort* orow = Opart + rowidx * 64;
#pragma unroll
  for (int r = 0; r < 16; r += 2) {
    const int d0 = (r & 3) + 8 * (r >> 2) + 4 * h;        // even, d1 = d0+1
    const uint32_t v0 = (uint32_t)f2bf(oacc0[r]) | ((uint32_t)f2bf(oacc0[r + 1]) << 16);
    const uint32_t v1 = (uint32_t)f2bf(oacc1[r]) | ((uint32_t)f2bf(oacc1[r + 1]) << 16);
    *(uint32_t*)(orow + d0)      = v0;
    *(uint32_t*)(orow + 32 + d0) = v1;
  }
  if (h == 0) mlbuf[rowidx] = make_float2(mrun, lrun);
}

// ---------- combine the two KV-halves: one wave per q-row ----------
__global__ __launch_bounds__(256) void combine_kernel(const ushort* __restrict__ Opart,
                                                      const float2* __restrict__ mlbuf,
                                                      ushort* __restrict__ AO) {
  const int gid = blockIdx.x * 4 + (threadIdx.x >> 6);   // [0, 65536) = bh*2048+q
  const int lane = threadIdx.x & 63;
  const int bh = gid >> 11, q = gid & 2047;
  const float2 a = mlbuf[(size_t)gid * 2 + 0];
  const float2 b = mlbuf[(size_t)gid * 2 + 1];
  const float M = fmaxf(a.x, b.x);
  const float wA = exp2f(a.x - M), wB = exp2f(b.x - M);
  const float inv = 1.f / (wA * a.y + wB * b.y);
  const float va = bf2f(Opart[(size_t)gid * 128 + lane]);
  const float vb = bf2f(Opart[(size_t)gid * 128 + 64 + lane]);
  const float val = (wA * va + wB * vb) * inv;
  const int bb = bh >> 4, hd = bh & 15;
  AO[((size_t)bb * TSEQ + q) * DMODEL + hd * DK + lane] = f2bf(val);
}

extern "C" void kernel_launch(void* const* d_in, const int* in_sizes, int n_in,
                              void* d_out, int out_size, void* d_ws, size_t ws_size,
                              hipStream_t stream) {
  (void)in_sizes; (void)n_in; (void)out_size; (void)ws_size;
  const float* x    = (const float*)d_in[0];
  const float* Wkqv = (const float*)d_in[1];
  const float* bkqv = (const float*)d_in[2];
  const float* Wo   = (const float*)d_in[3];
  const float* bo   = (const float*)d_in[4];
  float* out = (float*)d_out;

  char* ws = (char*)d_ws;
  const size_t MB = 1024 * 1024;
  ushort* x_bf   = (ushort*)(ws + 0);        //  8 MB [4096][1024]
  ushort* wkqv_t = (ushort*)(ws + 8 * MB);   //  6 MB [3072][1024]
  ushort* wo_t   = (ushort*)(ws + 14 * MB);  //  2 MB [1024][1024]
  ushort* Kbuf   = (ushort*)(ws + 16 * MB);  //  8 MB [32][2048][64]
  ushort* Qbuf   = (ushort*)(ws + 24 * MB);  //  8 MB (pre-scaled by QSCALE)
  ushort* Vbuf   = (ushort*)(ws + 32 * MB);  //  8 MB
  ushort* Vtbuf  = (ushort*)(ws + 40 * MB);  //  8 MB [32][64][2048]
  ushort* AObuf  = (ushort*)(ws + 48 * MB);  //  8 MB [4096][1024]
  ushort* Opart  = (ushort*)(ws + 56 * MB);  // 16 MB [32][2048][2][64]
  float2* mlbuf  = (float2*)(ws + 72 * MB);  //  1 MB [32][2048][2]

  cvt_bf16_kernel<<<2048, 256, 0, stream>>>(x, x_bf, MTOT * DMODEL);
  transpose_cvt_kernel<<<dim3(3072 / 64, 1024 / 64), 256, 0, stream>>>(Wkqv, wkqv_t, 1024, 3072);
  transpose_cvt_kernel<<<dim3(1024 / 64, 1024 / 64), 256, 0, stream>>>(Wo, wo_t, 1024, 1024);
  gemm_bt_kernel<0><<<dim3(3072 / 128, 4096 / 128), 256, 0, stream>>>(
      x_bf, wkqv_t, bkqv, Kbuf, Qbuf, Vbuf, nullptr, 3072, 1024);
  transpose_v_kernel<<<dim3(TSEQ / 64, 32), 256, 0, stream>>>(Vbuf, Vtbuf);
  attn_kernel<<<1024, 256, 0, stream>>>(Qbuf, Kbuf, Vtbuf, Opart, mlbuf);
  combine_kernel<<<16384, 256, 0, stream>>>(Opart, mlbuf, AObuf);
  gemm_bt_kernel<1><<<dim3(1024 / 128, 4096 / 128), 256, 0, stream>>>(
      AObuf, wo_t, bo, nullptr, nullptr, nullptr, out, 1024, 1024);
}

// Round 6
// 215.540 us; speedup vs baseline: 1.3040x; 1.0053x over previous
//
#include <hip/hip_runtime.h>
#include <hip/hip_bf16.h>
#include <stdint.h>
#include <math.h>

using bf16x8 = __attribute__((ext_vector_type(8))) short;
using f32x4  = __attribute__((ext_vector_type(4))) float;
using f32x16 = __attribute__((ext_vector_type(16))) float;

#define NHEAD  16
#define DK     64
#define TSEQ   2048
#define DMODEL 1024
#define MTOT   4096   // B*T

// 0.125 (1/sqrt(dk)) * log2(e): folded into Q at the KQV epilogue so the
// flash softmax uses bare exp2.
#define QSCALE 0.18033688011112042f

static __device__ __forceinline__ ushort f2bf(float f) {
  union { float f; uint32_t u; } v; v.f = f;
  return (ushort)((v.u + 0x7FFFu + ((v.u >> 16) & 1u)) >> 16);   // RNE
}

static __device__ __forceinline__ float bf2f(ushort u) {
  union { uint32_t u; float f; } v; v.u = ((uint32_t)u) << 16;
  return v.f;
}

static __device__ __forceinline__ uint32_t cvtpk_bf16(float lo, float hi) {
  uint32_t r;
  asm("v_cvt_pk_bf16_f32 %0, %1, %2" : "=v"(r) : "v"(lo), "v"(hi));
  return r;
}

static __device__ __forceinline__ void gload_lds16(const ushort* g, ushort* l) {
  typedef __attribute__((address_space(1))) const uint32_t gu32;
  typedef __attribute__((address_space(3))) uint32_t lu32;
  __builtin_amdgcn_global_load_lds((gu32*)g, (lu32*)l, 16, 0, 0);
}

// ---------- f32 -> bf16 elementwise (vectorized, G13) ----------
__global__ void cvt_bf16_kernel(const float* __restrict__ in, ushort* __restrict__ out, int n) {
  int i = (blockIdx.x * 256 + threadIdx.x) * 8;
  const int stride = gridDim.x * 256 * 8;
  for (; i < n; i += stride) {
    const float4* p = (const float4*)(in + i);
    float4 a = p[0], b = p[1];
    bf16x8 v;
    v[0]=(short)f2bf(a.x); v[1]=(short)f2bf(a.y); v[2]=(short)f2bf(a.z); v[3]=(short)f2bf(a.w);
    v[4]=(short)f2bf(b.x); v[5]=(short)f2bf(b.y); v[6]=(short)f2bf(b.z); v[7]=(short)f2bf(b.w);
    *(bf16x8*)(out + i) = v;
  }
}

// ---------- W[K][N] f32  ->  Wt[N][K] bf16 (LDS-tiled transpose) ----------
__global__ __launch_bounds__(256) void transpose_cvt_kernel(const float* __restrict__ W,
                                                            ushort* __restrict__ Wt, int K, int N) {
  __shared__ ushort tl[64][66];
  const int n0 = blockIdx.x * 64, k0 = blockIdx.y * 64;
  const int c = threadIdx.x & 63, r0 = threadIdx.x >> 6;
#pragma unroll
  for (int i = 0; i < 64; i += 4)
    tl[i + r0][c] = f2bf(W[(size_t)(k0 + i + r0) * N + n0 + c]);
  __syncthreads();
#pragma unroll
  for (int i = 0; i < 64; i += 4)
    Wt[(size_t)(n0 + i + r0) * K + k0 + c] = tl[c][i + r0];
}

// ---------- V[bh][T][64] bf16 -> Vt[bh][64][T] bf16 ----------
__global__ __launch_bounds__(256) void transpose_v_kernel(const ushort* __restrict__ V,
                                                          ushort* __restrict__ Vt) {
  __shared__ ushort tl[64][66];
  const int bh = blockIdx.y, t0 = blockIdx.x * 64;
  const int c = threadIdx.x & 63, r0 = threadIdx.x >> 6;
  const ushort* Vb = V + (size_t)bh * TSEQ * DK;
  ushort* Vtb = Vt + (size_t)bh * DK * TSEQ;
#pragma unroll
  for (int i = 0; i < 64; i += 4)
    tl[i + r0][c] = Vb[(size_t)(t0 + i + r0) * DK + c];
  __syncthreads();
#pragma unroll
  for (int i = 0; i < 64; i += 4)
    Vtb[(size_t)(i + r0) * TSEQ + t0 + c] = tl[c][i + r0];
}

// ---------- m97-style bf16 GEMM, C = A[M][K] * Bt[N][K]^T + bias ----------
// MODE 0: scatters K,Q,V (bf16) into [B,H,T,dk], Q pre-scaled by QSCALE;
// MODE 1: fp32 out [M][N]
template <int MODE>
__global__ __launch_bounds__(256, 3)
void gemm_bt_kernel(const ushort* __restrict__ A, const ushort* __restrict__ Bt,
                    const float* __restrict__ bias,
                    ushort* __restrict__ oK, ushort* __restrict__ oQ, ushort* __restrict__ oV,
                    float* __restrict__ oF, int N, int K) {
  __shared__ ushort As[128 * 32];
  __shared__ ushort Bs[128 * 32];
  const int tid = threadIdx.x;
  const int w = tid >> 6, lane = tid & 63;
  const int m0 = blockIdx.y * 128, n0 = blockIdx.x * 128;
  const int wr = (w >> 1) * 64, wc = (w & 1) * 64;

  const int e0 = ((w * 2 + 0) * 64 + lane) * 8;
  const int e1 = ((w * 2 + 1) * 64 + lane) * 8;
  const ushort* pA0 = A  + (size_t)(m0 + (e0 >> 5)) * K + (e0 & 31);
  const ushort* pA1 = A  + (size_t)(m0 + (e1 >> 5)) * K + (e1 & 31);
  const ushort* pB0 = Bt + (size_t)(n0 + (e0 >> 5)) * K + (e0 & 31);
  const ushort* pB1 = Bt + (size_t)(n0 + (e1 >> 5)) * K + (e1 & 31);

  f32x4 acc[4][4];
#pragma unroll
  for (int i = 0; i < 4; i++)
#pragma unroll
    for (int j = 0; j < 4; j++) acc[i][j] = (f32x4){0.f, 0.f, 0.f, 0.f};

  const int aro = (wr + (lane & 15)) * 32 + (lane >> 4) * 8;
  const int bro = (wc + (lane & 15)) * 32 + (lane >> 4) * 8;

  for (int k0 = 0; k0 < K; k0 += 32) {
    __syncthreads();
    gload_lds16(pA0 + k0, &As[e0]);
    gload_lds16(pA1 + k0, &As[e1]);
    gload_lds16(pB0 + k0, &Bs[e0]);
    gload_lds16(pB1 + k0, &Bs[e1]);
    __syncthreads();
    bf16x8 af[4], bfr[4];
#pragma unroll
    for (int i = 0; i < 4; i++) af[i]  = *(const bf16x8*)&As[aro + i * 16 * 32];
#pragma unroll
    for (int j = 0; j < 4; j++) bfr[j] = *(const bf16x8*)&Bs[bro + j * 16 * 32];
#pragma unroll
    for (int i = 0; i < 4; i++)
#pragma unroll
      for (int j = 0; j < 4; j++)
        acc[i][j] = __builtin_amdgcn_mfma_f32_16x16x32_bf16(af[i], bfr[j], acc[i][j], 0, 0, 0);
  }

  const int rbase = m0 + wr + (lane >> 4) * 4;
  const int cbase = n0 + wc + (lane & 15);
#pragma unroll
  for (int i = 0; i < 4; i++) {
#pragma unroll
    for (int j = 0; j < 4; j++) {
      const int gn = cbase + j * 16;
      const float bv = bias[gn];
#pragma unroll
      for (int jj = 0; jj < 4; jj++) {
        const int gm = rbase + i * 16 + jj;
        float val = acc[i][j][jj] + bv;
        if (MODE == 0) {
          const int sel = gn >> 10, cc = gn & 1023;
          const int hh = cc >> 6, dd = cc & 63;
          const int bbx = gm >> 11, t = gm & 2047;
          if (sel == 1) val *= QSCALE;   // pre-scale Q (before bf16 round)
          ushort* dst = (sel == 0) ? oK : (sel == 1) ? oQ : oV;
          dst[((size_t)((bbx * NHEAD + hh) * TSEQ + t)) * DK + dd] = f2bf(val);
        } else {
          oF[(size_t)gm * N + gn] = val;
        }
      }
    }
  }
}

// ---------- causal flash attention, swapped-QK^T + chunked split-KV ----------
// 1280 pieces = 32 bh x 40 chunks (<=8 KV-tiles each; np(qi)=qi/4+1 pieces per
// 128-row q-tile). 4 waves x 32 q-rows; S = mfma(K,Q) -> lane owns a q-row;
// softmax in-register; PV = mfma(Vt,P). Unnormalized O (bf16) + (m,l) partials.
__global__ __launch_bounds__(256, 4)
void attn_kernel(const ushort* __restrict__ Qb, const ushort* __restrict__ Kb,
                 const ushort* __restrict__ Vtb, ushort* __restrict__ Opart,
                 float2* __restrict__ mlbuf) {
  __shared__ ushort Ks[2][64 * 64];    // [kv][dk], XOR-swizzled 16B blocks, dbuf
  __shared__ ushort Vs[2][64 * 64];    // [d][kv], XOR-swizzled, dbuf

  // XCD-grouped mapping (pieces of one bh stay on one XCD); LPT (big qi first)
  const int bid = blockIdx.x;
  const int xcd = bid & 7, i = bid >> 3;            // i in [0,160)
  const int bh = xcd + 8 * (i / 40);
  const int jj = 39 - (i % 40);                     // LPT: decode big pieces first
  int qi, p;
  if (jj < 4)       { qi = jj;                 p = 0; }
  else if (jj < 12) { int t = jj - 4;  qi = 4  + (t >> 1); p = t & 1; }
  else if (jj < 24) { int t = jj - 12; qi = 8  + t / 3;    p = t % 3; }
  else              { int t = jj - 24; qi = 12 + (t >> 2); p = t & 3; }

  const int q0 = qi * 128;
  const int tid = threadIdx.x, w = tid >> 6, lane = tid & 63;
  const int l31 = lane & 31, h = lane >> 5;         // h = wave half
  const int qrow = q0 + w * 32 + l31;               // this lane's q-row

  // piece KV-tile range: [p*8, min(p*8+8, 2qi+2))
  const int t_begin = p * 8;
  const int ntp = min(t_begin + 8, 2 * qi + 2) - t_begin;

  // Q fragments: B-operand of 32x32x16 -> B[n=q=l31][k=(h*8+j)], 4 dk-slices
  const ushort* Qp = Qb + ((size_t)bh * TSEQ + qrow) * DK;
  bf16x8 qf[4];
#pragma unroll
  for (int c = 0; c < 4; c++)
    qf[c] = *(const bf16x8*)(Qp + c * 16 + h * 8);

  f32x16 oacc0, oacc1;                 // out[d = dh*32 + (r&3)+8*(r>>2)+4h][q=l31]
#pragma unroll
  for (int r = 0; r < 16; r++) { oacc0[r] = 0.f; oacc1[r] = 0.f; }
  float mrun = -INFINITY, lrun = 0.f;  // per-lane = per-q-row (both halves agree)

  // staging: linear LDS dest + inverse-swizzled global source (rule #21)
  const int Bl0 = w * 128 + lane, Bl1 = Bl0 + 64;
  const int sr0 = Bl0 >> 3, sc0 = ((Bl0 & 7) ^ (sr0 & 7)) * 8;
  const int sr1 = Bl1 >> 3, sc1 = ((Bl1 & 7) ^ (sr1 & 7)) * 8;
  const ushort* Kp0 = Kb  + (size_t)bh * TSEQ * DK + sr0 * DK + sc0;
  const ushort* Kp1 = Kb  + (size_t)bh * TSEQ * DK + sr1 * DK + sc1;
  const ushort* Vp0 = Vtb + (size_t)bh * DK * TSEQ + sr0 * TSEQ + sc0;
  const ushort* Vp1 = Vtb + (size_t)bh * DK * TSEQ + sr1 * TSEQ + sc1;

  // prologue: stage tile t_begin into buf 0, drain, barrier
  {
    const int s0 = t_begin * 64;
    gload_lds16(Kp0 + s0 * DK, &Ks[0][Bl0 * 8]);
    gload_lds16(Kp1 + s0 * DK, &Ks[0][Bl1 * 8]);
    gload_lds16(Vp0 + s0, &Vs[0][Bl0 * 8]);
    gload_lds16(Vp1 + s0, &Vs[0][Bl1 * 8]);
  }
  asm volatile("s_waitcnt vmcnt(0)" ::: "memory");
  __builtin_amdgcn_s_barrier();

  for (int tt = 0; tt < ntp; tt++) {
    const int s0 = (t_begin + tt) * 64, cur = tt & 1;

    if (tt + 1 < ntp) {
      const int sn = (t_begin + tt + 1) * 64, nb = cur ^ 1;
      gload_lds16(Kp0 + sn * DK, &Ks[nb][Bl0 * 8]);
      gload_lds16(Kp1 + sn * DK, &Ks[nb][Bl1 * 8]);
      gload_lds16(Vp0 + sn, &Vs[nb][Bl0 * 8]);
      gload_lds16(Vp1 + sn, &Vs[nb][Bl1 * 8]);
    }

    const bool active = (s0 <= q0 + w * 32 + 31);   // wave-uniform
    if (active) {
      // ---- S = K x Q : D[col=q=l31][row=kv_local] ----
      f32x16 ps0, ps1;
#pragma unroll
      for (int r = 0; r < 16; r++) { ps0[r] = 0.f; ps1[r] = 0.f; }
      const char* Kbase = (const char*)&Ks[cur][0];
      __builtin_amdgcn_s_setprio(1);
#pragma unroll
      for (int c = 0; c < 4; c++) {
        const int r0 = l31, r1 = 32 + l31;
        bf16x8 kf0 = *(const bf16x8*)(Kbase + r0 * 128 + ((c * 32 + h * 16) ^ ((r0 & 7) << 4)));
        bf16x8 kf1 = *(const bf16x8*)(Kbase + r1 * 128 + ((c * 32 + h * 16) ^ ((r1 & 7) << 4)));
        ps0 = __builtin_amdgcn_mfma_f32_32x32x16_bf16(kf0, qf[c], ps0, 0, 0, 0);
        ps1 = __builtin_amdgcn_mfma_f32_32x32x16_bf16(kf1, qf[c], ps1, 0, 0, 0);
      }
      __builtin_amdgcn_s_setprio(0);

      // ---- mask (boundary tiles only) ----
      if (s0 + 63 > q0 + w * 32) {
#pragma unroll
        for (int r = 0; r < 16; r++) {
          const int kv0 = s0 + (r & 3) + 8 * (r >> 2) + 4 * h;
          if (kv0 > qrow)      ps0[r] = -INFINITY;
          if (kv0 + 32 > qrow) ps1[r] = -INFINITY;
        }
      }

      // ---- in-register row max (lane = q-row) ----
      float pm = ps0[0];
#pragma unroll
      for (int r = 1; r < 16; r++) pm = fmaxf(pm, ps0[r]);
#pragma unroll
      for (int r = 0; r < 16; r++) pm = fmaxf(pm, ps1[r]);
      pm = fmaxf(pm, __shfl_xor(pm, 32));

      // ---- defer-max (T13): rescale only when max grew > 8 (log2 units) ----
      if (!__all(pm <= mrun + 8.0f)) {
        const float nm = fmaxf(mrun, pm);
        const float scl = exp2f(mrun - nm);
        lrun *= scl;
#pragma unroll
        for (int r = 0; r < 16; r++) { oacc0[r] *= scl; oacc1[r] *= scl; }
        mrun = nm;
      }

      // ---- exp2 + row sum ----
#pragma unroll
      for (int r = 0; r < 16; r++) ps0[r] = exp2f(ps0[r] - mrun);
#pragma unroll
      for (int r = 0; r < 16; r++) ps1[r] = exp2f(ps1[r] - mrun);
      float rs = 0.f;
#pragma unroll
      for (int r = 0; r < 16; r++) rs += ps0[r] + ps1[r];
      rs += __shfl_xor(rs, 32);
      lrun += rs;

      // ---- pack P to bf16 words ----
      uint32_t w0[2][4], w1[2][4];
#pragma unroll
      for (int a = 0; a < 4; a++) {
        w0[0][a] = cvtpk_bf16(ps0[4 * a + 0], ps0[4 * a + 1]);
        w1[0][a] = cvtpk_bf16(ps0[4 * a + 2], ps0[4 * a + 3]);
        w0[1][a] = cvtpk_bf16(ps1[4 * a + 0], ps1[4 * a + 1]);
        w1[1][a] = cvtpk_bf16(ps1[4 * a + 2], ps1[4 * a + 3]);
      }

      // ---- PV: per kv-16-slice t=2s+u, build P B-frag via half exchange ----
      const char* Vbase = (const char*)&Vs[cur][0];
#pragma unroll
      for (int s = 0; s < 2; s++) {
#pragma unroll
        for (int u = 0; u < 2; u++) {
          const int t = 2 * s + u;
          const uint32_t sw0 = h ? w0[s][2 * u] : w0[s][2 * u + 1];
          const uint32_t sw1 = h ? w1[s][2 * u] : w1[s][2 * u + 1];
          const uint32_t rx0 = (uint32_t)__shfl_xor((int)sw0, 32);
          const uint32_t rx1 = (uint32_t)__shfl_xor((int)sw1, 32);
          int4 pw;
          pw.x = h ? (int)rx0 : (int)w0[s][2 * u];
          pw.y = h ? (int)rx1 : (int)w1[s][2 * u];
          pw.z = h ? (int)w0[s][2 * u + 1] : (int)rx0;
          pw.w = h ? (int)w1[s][2 * u + 1] : (int)rx1;
          const bf16x8 pf = __builtin_bit_cast(bf16x8, pw);

          const int vr0 = l31, vr1 = 32 + l31;
          bf16x8 vf0 = *(const bf16x8*)(Vbase + vr0 * 128 + ((t * 32 + h * 16) ^ ((vr0 & 7) << 4)));
          bf16x8 vf1 = *(const bf16x8*)(Vbase + vr1 * 128 + ((t * 32 + h * 16) ^ ((vr1 & 7) << 4)));
          __builtin_amdgcn_s_setprio(1);
          oacc0 = __builtin_amdgcn_mfma_f32_32x32x16_bf16(vf0, pf, oacc0, 0, 0, 0);
          oacc1 = __builtin_amdgcn_mfma_f32_32x32x16_bf16(vf1, pf, oacc1, 0, 0, 0);
          __builtin_amdgcn_s_setprio(0);
        }
      }
    }

    asm volatile("s_waitcnt vmcnt(0)" ::: "memory");
    __builtin_amdgcn_s_barrier();
  }

  // ---- write partials: unnormalized O (bf16) + (m, l) ----
  const int partIdx = (bh * 16 + qi) * 4 + p;
  const size_t rowslot = (size_t)partIdx * 128 + (qrow & 127);
  ushort* orow = Opart + rowslot * 64;
#pragma unroll
  for (int r = 0; r < 16; r += 2) {
    const int d0 = (r & 3) + 8 * (r >> 2) + 4 * h;        // even, d1 = d0+1
    const uint32_t v0 = (uint32_t)f2bf(oacc0[r]) | ((uint32_t)f2bf(oacc0[r + 1]) << 16);
    const uint32_t v1 = (uint32_t)f2bf(oacc1[r]) | ((uint32_t)f2bf(oacc1[r + 1]) << 16);
    *(uint32_t*)(orow + d0)      = v0;
    *(uint32_t*)(orow + 32 + d0) = v1;
  }
  if (h == 0) mlbuf[rowslot] = make_float2(mrun, lrun);
}

// ---------- combine np(qi)=qi/4+1 partials: one wave per q-row ----------
__global__ __launch_bounds__(256) void combine_kernel(const ushort* __restrict__ Opart,
                                                      const float2* __restrict__ mlbuf,
                                                      ushort* __restrict__ AO) {
  const int gid = blockIdx.x * 4 + (threadIdx.x >> 6);   // [0, 65536) = bh*2048+q
  const int lane = threadIdx.x & 63;
  const int bh = gid >> 11, q = gid & 2047;
  const int qi = q >> 7, np = (qi >> 2) + 1;
  const size_t base = ((size_t)(bh * 16 + qi) * 4) * 128 + (q & 127);

  float M = -INFINITY;
  for (int p = 0; p < np; p++) M = fmaxf(M, mlbuf[base + (size_t)p * 128].x);
  float den = 0.f, acc = 0.f;
  for (int p = 0; p < np; p++) {
    const float2 ml = mlbuf[base + (size_t)p * 128];
    const float wp = exp2f(ml.x - M);
    den += wp * ml.y;
    acc += wp * bf2f(Opart[(base + (size_t)p * 128) * 64 + lane]);
  }
  const float val = acc / den;
  const int bb = bh >> 4, hd = bh & 15;
  AO[((size_t)bb * TSEQ + q) * DMODEL + hd * DK + lane] = f2bf(val);
}

extern "C" void kernel_launch(void* const* d_in, const int* in_sizes, int n_in,
                              void* d_out, int out_size, void* d_ws, size_t ws_size,
                              hipStream_t stream) {
  (void)in_sizes; (void)n_in; (void)out_size; (void)ws_size;
  const float* x    = (const float*)d_in[0];
  const float* Wkqv = (const float*)d_in[1];
  const float* bkqv = (const float*)d_in[2];
  const float* Wo   = (const float*)d_in[3];
  const float* bo   = (const float*)d_in[4];
  float* out = (float*)d_out;

  char* ws = (char*)d_ws;
  const size_t MB = 1024 * 1024;
  ushort* x_bf   = (ushort*)(ws + 0);        //  8 MB [4096][1024]
  ushort* wkqv_t = (ushort*)(ws + 8 * MB);   //  6 MB [3072][1024]
  ushort* wo_t   = (ushort*)(ws + 14 * MB);  //  2 MB [1024][1024]
  ushort* Kbuf   = (ushort*)(ws + 16 * MB);  //  8 MB [32][2048][64]
  ushort* Qbuf   = (ushort*)(ws + 24 * MB);  //  8 MB (pre-scaled by QSCALE)
  ushort* Vbuf   = (ushort*)(ws + 32 * MB);  //  8 MB
  ushort* Vtbuf  = (ushort*)(ws + 40 * MB);  //  8 MB [32][64][2048]
  ushort* AObuf  = (ushort*)(ws + 48 * MB);  //  8 MB [4096][1024]
  ushort* Opart  = (ushort*)(ws + 56 * MB);  // 32 MB [32][16][4][128][64]
  float2* mlbuf  = (float2*)(ws + 88 * MB);  //  2 MB [32][16][4][128]

  cvt_bf16_kernel<<<2048, 256, 0, stream>>>(x, x_bf, MTOT * DMODEL);
  transpose_cvt_kernel<<<dim3(3072 / 64, 1024 / 64), 256, 0, stream>>>(Wkqv, wkqv_t, 1024, 3072);
  transpose_cvt_kernel<<<dim3(1024 / 64, 1024 / 64), 256, 0, stream>>>(Wo, wo_t, 1024, 1024);
  gemm_bt_kernel<0><<<dim3(3072 / 128, 4096 / 128), 256, 0, stream>>>(
      x_bf, wkqv_t, bkqv, Kbuf, Qbuf, Vbuf, nullptr, 3072, 1024);
  transpose_v_kernel<<<dim3(TSEQ / 64, 32), 256, 0, stream>>>(Vbuf, Vtbuf);
  attn_kernel<<<1280, 256, 0, stream>>>(Qbuf, Kbuf, Vtbuf, Opart, mlbuf);
  combine_kernel<<<16384, 256, 0, stream>>>(Opart, mlbuf, AObuf);
  gemm_bt_kernel<1><<<dim3(1024 / 128, 4096 / 128), 256, 0, stream>>>(
      AObuf, wo_t, bo, nullptr, nullptr, nullptr, out, 1024, 1024);
}